// Round 8
// baseline (216.831 us; speedup 1.0000x reference)
//
#include <hip/hip_runtime.h>
#include <hip/hip_bf16.h>
#include <math.h>

typedef unsigned short u16;
typedef short bf16x8 __attribute__((ext_vector_type(8)));
typedef short bf16x4 __attribute__((ext_vector_type(4)));
typedef unsigned short u16x4 __attribute__((ext_vector_type(4)));
typedef float f32x4 __attribute__((ext_vector_type(4)));

#define MFMA(a,b,c)   __builtin_amdgcn_mfma_f32_16x16x32_bf16((a),(b),(c),0,0,0)
#define MFMA16(a,b,c) __builtin_amdgcn_mfma_f32_16x16x16bf16_1k((a),(b),(c),0,0,0)

// ws layout (u16 elements): pre-swizzled bf16 MFMA A/B fragments
#define WS_WK1 0
#define WS_WV1 8192
#define WS_WK2 16384
#define WS_WV2 24576
#define WS_WK3 32768
#define WS_WV3 69632
#define WS_WO  106496      // 144 frags (ct 36 x jt 4) x 256 u16, B-layout K=16
#define WS_TOTAL 143360

// LDS byte offsets (64 edges / 4 nodes per block) — total 50432 B
#define OFF_H1   0        // [2][64][72] u16 = 18432  (overlay: s_yp [8][4][64] f32)
#define OFF_H2   18432    // [64][72] u16 = 9216 (single buffer, k then v)
#define OFF_INV  27648    // [64][72] u16 = 9216      (overlay: s_lp [8][64][4] f32)
#define OFF_X    36864    // [64][72] u16 = 9216
#define OFF_SH   46080    // [64][8] f32 = 2048
#define OFF_Q    48128    // [4][64] f32 = 1024
#define OFF_CUT  49152    // [64] f32 = 256
#define OFF_WGT  49408    // [64][4] f32 = 1024
#define SMEM_SZ  50432

__device__ __forceinline__ u16 f2b(float f) {
    unsigned int u; __builtin_memcpy(&u, &f, 4);
    u += 0x7FFFu + ((u >> 16) & 1u);          // round-to-nearest-even
    return (u16)(u >> 16);
}
__device__ __forceinline__ float b2f(u16 v) {
    unsigned int u = ((unsigned int)v) << 16;
    float f; __builtin_memcpy(&f, &u, 4);
    return f;
}
// packed f32x2 -> bf16x2 (hw cvt_pk on gfx950)
__device__ __forceinline__ unsigned int f2b2(float x, float y) {
    __hip_bfloat162 h = __float22bfloat162_rn(make_float2(x, y));
    unsigned int u; __builtin_memcpy(&u, &h, 4);
    return u;
}
__device__ __forceinline__ u16x4 pack4(float4 v) {
    unsigned long long uu = ((unsigned long long)f2b2(v.z, v.w) << 32) | f2b2(v.x, v.y);
    u16x4 o; __builtin_memcpy(&o, &uu, 8);
    return o;
}
__device__ __forceinline__ float gelu(float x) {
    float u = 0.7978845608028654f * x * (1.0f + 0.044715f * x * x);
    u = fminf(fmaxf(u, -15.0f), 15.0f);
    float e = __expf(2.0f * u);
    float t = __fdividef(e - 1.0f, e + 1.0f);  // tanh(u)
    return 0.5f * x * (1.0f + t);
}

// ---------------- weight pre-swizzle: fp32 [K x N] -> bf16 MFMA frags ----------------
__global__ void prep(const float* __restrict__ Wk1, const float* __restrict__ Wk2,
                     const float* __restrict__ Wk3, const float* __restrict__ Wv1,
                     const float* __restrict__ Wv2, const float* __restrict__ Wv3,
                     const float* __restrict__ Wout, u16* __restrict__ wsw) {
    int i = blockIdx.x * 256 + threadIdx.x;
    if (i >= WS_TOTAL) return;
    if (i >= WS_WO) {
        // Wout as B-operand frags for v_mfma_f32_16x16x16_bf16:
        // frag f = ct*4+jt; lane l holds B[n=j][k=c]: n=jt*16+(l&15), k=ct*16+(l>>4)*4+j4
        int pos = i - WS_WO;
        int f = pos >> 8, idx = pos & 255;
        int l = idx >> 2, j4 = idx & 3;
        int ct = f >> 2, jt = f & 3;
        int c = ct * 16 + ((l >> 4) << 2) + j4;
        int j = jt * 16 + (l & 15);
        wsw[i] = f2b(Wout[c * 64 + j]);
        return;
    }
    const float* W; int Kd, Nd, pos;
    if      (i < WS_WV1) { W = Wk1;  Kd = 64;  Nd = 64;  pos = i; }
    else if (i < WS_WK2) { W = Wv1;  Kd = 64;  Nd = 64;  pos = i - WS_WV1; }
    else if (i < WS_WV2) { W = Wk2;  Kd = 64;  Nd = 64;  pos = i - WS_WK2; }
    else if (i < WS_WK3) { W = Wv2;  Kd = 64;  Nd = 64;  pos = i - WS_WV2; }
    else if (i < WS_WV3) { W = Wk3;  Kd = 64;  Nd = 576; pos = i - WS_WK3; }
    else                 { W = Wv3;  Kd = 64;  Nd = 576; pos = i - WS_WV3; }
    int f = pos >> 9, rr = pos & 511, l = rr >> 3, j = rr & 7;
    int ktN = Kd >> 5;
    int mt = f / ktN, kt = f - mt * ktN;
    int m = mt * 16 + (l & 15);
    int k = kt * 32 + ((l >> 4) << 3) + j;
    wsw[i] = f2b(W[k * Nd + m]);
}

// one (ct, et-range) task: D[16ch x 16e] tiles = W^T*act, gelu, store [e][ch] bf16
__device__ __forceinline__ void mlp_layer(const u16* __restrict__ Wf,
                                          const u16* __restrict__ sin,
                                          u16* __restrict__ sout,
                                          int ct, int lane, int et0, int et1) {
    const int q = lane >> 4, el = lane & 15;
    bf16x8 a0 = *(const bf16x8*)(Wf + (ct * 2 + 0) * 512 + lane * 8);
    bf16x8 a1 = *(const bf16x8*)(Wf + (ct * 2 + 1) * 512 + lane * 8);
    for (int et = et0; et < et1; ++et) {
        const u16* br = sin + (et * 16 + el) * 72 + q * 8;
        bf16x8 b0 = *(const bf16x8*)(br);
        bf16x8 b1 = *(const bf16x8*)(br + 32);
        f32x4 c = {0.f, 0.f, 0.f, 0.f};
        c = MFMA(a0, b0, c);
        c = MFMA(a1, b1, c);
        unsigned long long uu =
            ((unsigned long long)f2b2(gelu(c[2]), gelu(c[3])) << 32) |
            f2b2(gelu(c[0]), gelu(c[1]));
        u16x4 o; __builtin_memcpy(&o, &uu, 8);
        *(u16x4*)(sout + (et * 16 + el) * 72 + ct * 16 + q * 4) = o;
    }
}

__global__ __launch_bounds__(512, 4) void fused(
    const float* __restrict__ node_feat, const float* __restrict__ edge_sh,
    const float* __restrict__ edge_inv, const float* __restrict__ cutoff,
    const float* __restrict__ Wlogit, const int* __restrict__ edge_src,
    const u16* __restrict__ wsw, float* __restrict__ out)
{
    __shared__ __align__(16) unsigned char smem[SMEM_SZ];
    u16*   s_h1  = (u16*)(smem + OFF_H1);     // [2][64][72]
    u16*   s_h2  = (u16*)(smem + OFF_H2);     // [64][72] (k then v)
    u16*   s_inv = (u16*)(smem + OFF_INV);    // [64][72]
    u16*   s_x   = (u16*)(smem + OFF_X);      // [64][72]
    float* s_sh  = (float*)(smem + OFF_SH);   // [64][8]
    float* s_q   = (float*)(smem + OFF_Q);    // [4][64]
    float* s_cut = (float*)(smem + OFF_CUT);  // [64]
    float* s_wgt = (float*)(smem + OFF_WGT);  // [64][4]
    float* s_lp  = (float*)(smem + OFF_INV);  // overlay (inv dead after L1): [8][64][4]
    float* s_yp  = (float*)(smem + OFF_H1);   // overlay (h1k dead after L2k): [8][4][64]

    const int tid = threadIdx.x;
    const int lane = tid & 63;
    const int w = tid >> 6;
    const int q4 = lane >> 4;     // quad
    const int el = lane & 15;
    const int blk = blockIdx.x;
    const int n0 = blk * 4;
    const long e0 = (long)blk * 64;

    // ---------------- stage ----------------
    if (tid < 64)  s_cut[tid] = cutoff[e0 + tid];
    if (tid < 256) s_q[tid] = node_feat[(long)(n0 + (tid >> 6)) * 64 + (tid & 63)];
    s_sh[tid] = edge_sh[e0 * 8 + tid];
    { int row = tid >> 3, part = tid & 7;
      const float4* src = (const float4*)(edge_inv + (e0 + row) * 64) + part * 2;
      u16x4* dst = (u16x4*)(s_inv + row * 72 + part * 8);
      dst[0] = pack4(src[0]); dst[1] = pack4(src[1]);
      int sr = edge_src[e0 + row];
      const float4* sx = (const float4*)(node_feat + (long)sr * 64) + part * 2;
      u16x4* dx = (u16x4*)(s_x + row * 72 + part * 8);
      dx[0] = pack4(sx[0]); dx[1] = pack4(sx[1]);
    }
    __syncthreads();

    // ---------------- layer 1 (k & v in parallel across waves) ----------------
    const int mat = w >> 2, ct12 = w & 3;
    mlp_layer(wsw + (mat ? WS_WV1 : WS_WK1), s_inv, s_h1 + mat * 4608, ct12, lane, 0, 4);
    __syncthreads();

    // -------- prefetch k-path A-frags + Wlogit rows (overlap with L2k) --------
    bf16x8 ak0[5], ak1[5];
    float4 wlB[5];
#pragma unroll
    for (int ci = 0; ci < 5; ++ci) {
        int ct = w + 8 * ci;
        if (ct < 36) {
            const u16* Af = wsw + WS_WK3 + ct * 1024 + lane * 8;
            ak0[ci] = *(const bf16x8*)(Af);
            ak1[ci] = *(const bf16x8*)(Af + 512);
            if (ct >= 4) {
                int dd = 2 * (ct - 4) + (q4 >> 1);
                wlB[ci] = *(const float4*)(Wlogit + (64 + dd) * 4);
            }
        }
    }

    // ---------------- layer 2 (k only, all 8 waves: 4 ct x 2 et-halves) ----------------
    const int eh = w >> 2;
    mlp_layer(wsw + WS_WK2, s_h1, s_h2, ct12, lane, eh * 2, eh * 2 + 2);
    __syncthreads();

    // ---------------- layer 3 k-path + logits ----------------
    {
        float4 wlA[4];
        if (w < 4) {
#pragma unroll
            for (int r = 0; r < 4; ++r)
                wlA[r] = *(const float4*)(Wlogit + (w * 16 + 4 * q4 + r) * 4);
        }
#pragma unroll
        for (int et = 0; et < 4; ++et) {
            const u16* br = s_h2 + (et * 16 + el) * 72 + q4 * 8;
            bf16x8 b0 = *(const bf16x8*)(br);
            bf16x8 b1 = *(const bf16x8*)(br + 32);
            float L0 = 0.f, L1 = 0.f, L2 = 0.f, L3 = 0.f;
#pragma unroll
            for (int ci = 0; ci < 5; ++ci) {
                int ct = w + 8 * ci;
                if (ct < 36) {
                    f32x4 c = {0.f, 0.f, 0.f, 0.f};
                    c = MFMA(ak0[ci], b0, c);
                    c = MFMA(ak1[ci], b1, c);
                    if (ct < 4) {
                        const float* qp = s_q + et * 64 + ct * 16 + 4 * q4;
                        u16x4 xv = *(const u16x4*)(s_x + (et * 16 + el) * 72 + ct * 16 + 4 * q4);
#pragma unroll
                        for (int r = 0; r < 4; ++r) {
                            float wk = c[r] * qp[r] * b2f(xv[r]);
                            L0 += wk * wlA[r].x; L1 += wk * wlA[r].y;
                            L2 += wk * wlA[r].z; L3 += wk * wlA[r].w;
                        }
                    } else {
                        int dd = 2 * (ct - 4) + (q4 >> 1), sb = (q4 & 1) * 4;
                        float qd = s_q[et * 64 + dd];
                        float xd = b2f(s_x[(et * 16 + el) * 72 + dd]);
                        float4 sp = *(const float4*)(s_sh + (et * 16 + el) * 8 + sb);
                        float ss = c[0]*sp.x*sp.x + c[1]*sp.y*sp.y + c[2]*sp.z*sp.z + c[3]*sp.w*sp.w;
                        float wk = ss * qd * xd;
                        L0 += wk * wlB[ci].x; L1 += wk * wlB[ci].y;
                        L2 += wk * wlB[ci].z; L3 += wk * wlB[ci].w;
                    }
                }
            }
            L0 += __shfl_xor(L0, 16, 64); L0 += __shfl_xor(L0, 32, 64);
            L1 += __shfl_xor(L1, 16, 64); L1 += __shfl_xor(L1, 32, 64);
            L2 += __shfl_xor(L2, 16, 64); L2 += __shfl_xor(L2, 32, 64);
            L3 += __shfl_xor(L3, 16, 64); L3 += __shfl_xor(L3, 32, 64);
            if (lane < 16) {
                float* p = s_lp + w * 256 + (et * 16 + lane) * 4;
                p[0] = L0; p[1] = L1; p[2] = L2; p[3] = L3;
            }
        }
    }
    __syncthreads();

    // -------- prefetch v-path A-frags (overlap with softmax + L2v) --------
    bf16x8 av0[5], av1[5];
#pragma unroll
    for (int ci = 0; ci < 5; ++ci) {
        int ct = w + 8 * ci;
        if (ct < 36) {
            const u16* Af = wsw + WS_WV3 + ct * 1024 + lane * 8;
            av0[ci] = *(const bf16x8*)(Af);
            av1[ci] = *(const bf16x8*)(Af + 512);
        }
    }

    // -------- softmax (wave 0) concurrent with layer 2 (v, all waves) --------
    if (w == 0) {
        float l4[4] = {0.f, 0.f, 0.f, 0.f};
#pragma unroll
        for (int ww = 0; ww < 8; ++ww) {
            float4 p = *(const float4*)(s_lp + ww * 256 + lane * 4);
            l4[0] += p.x; l4[1] += p.y; l4[2] += p.z; l4[3] += p.w;
        }
        float cut = s_cut[lane];
        float wg[4];
#pragma unroll
        for (int h = 0; h < 4; ++h) {
            float m = l4[h];
            m = fmaxf(m, __shfl_xor(m, 1, 64));
            m = fmaxf(m, __shfl_xor(m, 2, 64));
            m = fmaxf(m, __shfl_xor(m, 4, 64));
            m = fmaxf(m, __shfl_xor(m, 8, 64));
            float ex = cut * __expf(l4[h] - m);
            float z = ex;
            z += __shfl_xor(z, 1, 64);
            z += __shfl_xor(z, 2, 64);
            z += __shfl_xor(z, 4, 64);
            z += __shfl_xor(z, 8, 64);
            if (z == 0.f) z = 1.f;
            float a = __fdividef(ex, z);
            wg[h] = sqrtf(fmaxf(a, 0.f));
        }
        float4 o; o.x = wg[0]; o.y = wg[1]; o.z = wg[2]; o.w = wg[3];
        *(float4*)(s_wgt + lane * 4) = o;
    }
    mlp_layer(wsw + WS_WV2, s_h1 + 4608, s_h2, ct12, lane, eh * 2, eh * 2 + 2);
    __syncthreads();

    // ---- layer 3 v-path + weighting + per-edge Wout projection (MFMA K=16) ----
    {
#pragma unroll
        for (int et = 0; et < 4; ++et) {
            const u16* br = s_h2 + (et * 16 + el) * 72 + q4 * 8;
            bf16x8 b0 = *(const bf16x8*)(br);
            bf16x8 b1 = *(const bf16x8*)(br + 32);
            float4 wg4 = *(const float4*)(s_wgt + (et * 16 + el) * 4);
            f32x4 accj[4];
#pragma unroll
            for (int jt = 0; jt < 4; ++jt) accj[jt] = (f32x4){0.f, 0.f, 0.f, 0.f};
#pragma unroll
            for (int ci = 0; ci < 5; ++ci) {
                int ct = w + 8 * ci;
                if (ct < 36) {
                    f32x4 c = {0.f, 0.f, 0.f, 0.f};
                    c = MFMA(av0[ci], b0, c);
                    c = MFMA(av1[ci], b1, c);
                    int c0q = ct * 16 + 4 * q4;
                    int h = (c0q >= 432) ? 3 : (c0q >= 288) ? 2 : (c0q >= 144) ? 1 : 0;
                    float wgt = (h == 0) ? wg4.x : (h == 1) ? wg4.y : (h == 2) ? wg4.z : wg4.w;
                    float v0, v1, v2, v3;
                    if (ct < 4) {
                        u16x4 xv = *(const u16x4*)(s_x + (et * 16 + el) * 72 + c0q);
                        v0 = c[0] * b2f(xv[0]) * wgt;
                        v1 = c[1] * b2f(xv[1]) * wgt;
                        v2 = c[2] * b2f(xv[2]) * wgt;
                        v3 = c[3] * b2f(xv[3]) * wgt;
                    } else {
                        int dd = 2 * (ct - 4) + (q4 >> 1), sb = (q4 & 1) * 4;
                        float xd = b2f(s_x[(et * 16 + el) * 72 + dd]) * wgt;
                        float4 shp = *(const float4*)(s_sh + (et * 16 + el) * 8 + sb);
                        v0 = c[0] * xd * shp.x;
                        v1 = c[1] * xd * shp.y;
                        v2 = c[2] * xd * shp.z;
                        v3 = c[3] * xd * shp.w;
                    }
                    // weighted values: A-frag layout for K=16 MFMA (m=edge el, k=4q4+r)
                    unsigned long long uu =
                        ((unsigned long long)f2b2(v2, v3) << 32) | f2b2(v0, v1);
                    bf16x4 aw; __builtin_memcpy(&aw, &uu, 8);
#pragma unroll
                    for (int jt = 0; jt < 4; ++jt) {
                        bf16x4 bw = *(const bf16x4*)(wsw + WS_WO + (size_t)(ct * 4 + jt) * 256 + lane * 4);
                        accj[jt] = MFMA16(aw, bw, accj[jt]);
                    }
                }
            }
            // D[m=edge 4q4+r][n=j jt*16+el]: sum own 4 edges, then cross-q4 -> node sum
#pragma unroll
            for (int jt = 0; jt < 4; ++jt) {
                float s = accj[jt][0] + accj[jt][1] + accj[jt][2] + accj[jt][3];
                s += __shfl_xor(s, 16, 64);
                s += __shfl_xor(s, 32, 64);
                if (q4 == 0) s_yp[(w * 4 + et) * 64 + jt * 16 + el] = s;
            }
        }
    }
    __syncthreads();

    // ---------------- final: sum the 8 wave partials per node ----------------
    if (tid < 256) {
        int et = tid >> 6, j = tid & 63;
        float r = 0.f;
#pragma unroll
        for (int ww = 0; ww < 8; ++ww) r += s_yp[(ww * 4 + et) * 64 + j];
        out[(long)(n0 + et) * 64 + j] = r;
    }
}

extern "C" void kernel_launch(void* const* d_in, const int* in_sizes, int n_in,
                              void* d_out, int out_size, void* d_ws, size_t ws_size,
                              hipStream_t stream) {
    const float* node_feat = (const float*)d_in[0];
    const float* edge_sh   = (const float*)d_in[1];
    const float* edge_inv  = (const float*)d_in[2];
    const float* cutoff    = (const float*)d_in[3];
    const float* Wk1       = (const float*)d_in[4];
    const float* Wk2       = (const float*)d_in[5];
    const float* Wk3       = (const float*)d_in[6];
    const float* Wv1       = (const float*)d_in[7];
    const float* Wv2       = (const float*)d_in[8];
    const float* Wv3       = (const float*)d_in[9];
    const float* Wlogit    = (const float*)d_in[10];
    const float* Wout      = (const float*)d_in[11];
    const int*   edge_src  = (const int*)d_in[12];
    float* out = (float*)d_out;
    u16* wsw = (u16*)d_ws;

    prep<<<(WS_TOTAL + 255) / 256, 256, 0, stream>>>(
        Wk1, Wk2, Wk3, Wv1, Wv2, Wv3, Wout, wsw);
    fused<<<2048, 512, 0, stream>>>(
        node_feat, edge_sh, edge_inv, cutoff, Wlogit, edge_src, wsw, out);
}

// Round 9
// 204.695 us; speedup vs baseline: 1.0593x; 1.0593x over previous
//
#include <hip/hip_runtime.h>
#include <hip/hip_bf16.h>
#include <math.h>

typedef unsigned short u16;
typedef short bf16x8 __attribute__((ext_vector_type(8)));
typedef short bf16x4 __attribute__((ext_vector_type(4)));
typedef unsigned short u16x4 __attribute__((ext_vector_type(4)));
typedef float f32x4 __attribute__((ext_vector_type(4)));

#define MFMA(a,b,c)   __builtin_amdgcn_mfma_f32_16x16x32_bf16((a),(b),(c),0,0,0)
#define MFMA16(a,b,c) __builtin_amdgcn_mfma_f32_16x16x16bf16_1k((a),(b),(c),0,0,0)

// ws layout (u16 elements): pre-swizzled bf16 MFMA A/B fragments
#define WS_WK1 0
#define WS_WV1 8192
#define WS_WK2 16384
#define WS_WV2 24576
#define WS_WK3 32768
#define WS_WV3 69632
#define WS_WO  106496      // 144 frags (ct 36 x jt 4) x 256 u16, B-layout K=16
#define WS_TOTAL 143360

// LDS byte offsets (64 edges / 4 nodes per block) — total 52480 B
#define OFF_H1   0        // [2][64][72] u16 = 18432  (overlay: s_yp [8][4][64] f32)
#define OFF_H2   18432    // [64][72] u16 = 9216 (single buffer, k then v)
#define OFF_INV  27648    // [64][72] u16 = 9216      (overlay: s_lp [8][64][4] f32)
#define OFF_X    36864    // [64][72] u16 = 9216
#define OFF_SH   46080    // [64][8] f32 = 2048
#define OFF_Q    48128    // [4][64] f32 = 1024
#define OFF_CUT  49152    // [64] f32 = 256
#define OFF_WL   49408    // [128][4] f32 = 2048
#define OFF_WGT  51456    // [64][4] f32 = 1024
#define SMEM_SZ  52480

__device__ __forceinline__ u16 f2b(float f) {
    unsigned int u; __builtin_memcpy(&u, &f, 4);
    u += 0x7FFFu + ((u >> 16) & 1u);          // round-to-nearest-even
    return (u16)(u >> 16);
}
__device__ __forceinline__ float b2f(u16 v) {
    unsigned int u = ((unsigned int)v) << 16;
    float f; __builtin_memcpy(&f, &u, 4);
    return f;
}
// packed f32x2 -> bf16x2 (hw cvt_pk on gfx950) — zero extra register cost
__device__ __forceinline__ unsigned int f2b2(float x, float y) {
    __hip_bfloat162 h = __float22bfloat162_rn(make_float2(x, y));
    unsigned int u; __builtin_memcpy(&u, &h, 4);
    return u;
}
__device__ __forceinline__ u16x4 pack4(float4 v) {
    unsigned long long uu = ((unsigned long long)f2b2(v.z, v.w) << 32) | f2b2(v.x, v.y);
    u16x4 o; __builtin_memcpy(&o, &uu, 8);
    return o;
}
__device__ __forceinline__ float gelu(float x) {
    float u = 0.7978845608028654f * x * (1.0f + 0.044715f * x * x);
    u = fminf(fmaxf(u, -15.0f), 15.0f);
    float e = __expf(2.0f * u);
    float t = __fdividef(e - 1.0f, e + 1.0f);  // tanh(u)
    return 0.5f * x * (1.0f + t);
}

// ---------------- weight pre-swizzle: fp32 [K x N] -> bf16 MFMA frags ----------------
__global__ void prep(const float* __restrict__ Wk1, const float* __restrict__ Wk2,
                     const float* __restrict__ Wk3, const float* __restrict__ Wv1,
                     const float* __restrict__ Wv2, const float* __restrict__ Wv3,
                     const float* __restrict__ Wout, u16* __restrict__ wsw) {
    int i = blockIdx.x * 256 + threadIdx.x;
    if (i >= WS_TOTAL) return;
    if (i >= WS_WO) {
        // Wout as B-operand frags for v_mfma_f32_16x16x16_bf16:
        // frag f = ct*4+jt; lane l holds B[n=j][k=c]: n=jt*16+(l&15), k=ct*16+(l>>4)*4+j4
        int pos = i - WS_WO;
        int f = pos >> 8, idx = pos & 255;
        int l = idx >> 2, j4 = idx & 3;
        int ct = f >> 2, jt = f & 3;
        int c = ct * 16 + ((l >> 4) << 2) + j4;
        int j = jt * 16 + (l & 15);
        wsw[i] = f2b(Wout[c * 64 + j]);
        return;
    }
    const float* W; int Kd, Nd, pos;
    if      (i < WS_WV1) { W = Wk1;  Kd = 64;  Nd = 64;  pos = i; }
    else if (i < WS_WK2) { W = Wv1;  Kd = 64;  Nd = 64;  pos = i - WS_WV1; }
    else if (i < WS_WV2) { W = Wk2;  Kd = 64;  Nd = 64;  pos = i - WS_WK2; }
    else if (i < WS_WK3) { W = Wv2;  Kd = 64;  Nd = 64;  pos = i - WS_WV2; }
    else if (i < WS_WV3) { W = Wk3;  Kd = 64;  Nd = 576; pos = i - WS_WK3; }
    else                 { W = Wv3;  Kd = 64;  Nd = 576; pos = i - WS_WV3; }
    int f = pos >> 9, rr = pos & 511, l = rr >> 3, j = rr & 7;
    int ktN = Kd >> 5;
    int mt = f / ktN, kt = f - mt * ktN;
    int m = mt * 16 + (l & 15);
    int k = kt * 32 + ((l >> 4) << 3) + j;
    wsw[i] = f2b(W[k * Nd + m]);
}

// one (ct, et-range) task: D[16ch x 16e] tiles = W^T*act, gelu, store [e][ch] bf16
__device__ __forceinline__ void mlp_layer(const u16* __restrict__ Wf,
                                          const u16* __restrict__ sin,
                                          u16* __restrict__ sout,
                                          int ct, int lane, int et0, int et1) {
    const int q = lane >> 4, el = lane & 15;
    bf16x8 a0 = *(const bf16x8*)(Wf + (ct * 2 + 0) * 512 + lane * 8);
    bf16x8 a1 = *(const bf16x8*)(Wf + (ct * 2 + 1) * 512 + lane * 8);
    for (int et = et0; et < et1; ++et) {
        const u16* br = sin + (et * 16 + el) * 72 + q * 8;
        bf16x8 b0 = *(const bf16x8*)(br);
        bf16x8 b1 = *(const bf16x8*)(br + 32);
        f32x4 c = {0.f, 0.f, 0.f, 0.f};
        c = MFMA(a0, b0, c);
        c = MFMA(a1, b1, c);
        unsigned long long uu =
            ((unsigned long long)f2b2(gelu(c[2]), gelu(c[3])) << 32) |
            f2b2(gelu(c[0]), gelu(c[1]));
        u16x4 o; __builtin_memcpy(&o, &uu, 8);
        *(u16x4*)(sout + (et * 16 + el) * 72 + ct * 16 + q * 4) = o;
    }
}

__global__ __launch_bounds__(512, 4) void fused(
    const float* __restrict__ node_feat, const float* __restrict__ edge_sh,
    const float* __restrict__ edge_inv, const float* __restrict__ cutoff,
    const float* __restrict__ Wlogit, const int* __restrict__ edge_src,
    const u16* __restrict__ wsw, float* __restrict__ out)
{
    __shared__ __align__(16) unsigned char smem[SMEM_SZ];
    u16*   s_h1  = (u16*)(smem + OFF_H1);     // [2][64][72]
    u16*   s_h2  = (u16*)(smem + OFF_H2);     // [64][72] (k then v)
    u16*   s_inv = (u16*)(smem + OFF_INV);    // [64][72]
    u16*   s_x   = (u16*)(smem + OFF_X);      // [64][72]
    float* s_sh  = (float*)(smem + OFF_SH);   // [64][8]
    float* s_q   = (float*)(smem + OFF_Q);    // [4][64]
    float* s_cut = (float*)(smem + OFF_CUT);  // [64]
    float* s_wl  = (float*)(smem + OFF_WL);   // [128][4]
    float* s_wgt = (float*)(smem + OFF_WGT);  // [64][4]
    float* s_lp  = (float*)(smem + OFF_INV);  // overlay (inv dead after L1): [8][64][4]
    float* s_yp  = (float*)(smem + OFF_H1);   // overlay (h1k dead after L2k): [8][4][64]

    const int tid = threadIdx.x;
    const int lane = tid & 63;
    const int w = tid >> 6;
    const int q4 = lane >> 4;     // quad
    const int el = lane & 15;
    const int blk = blockIdx.x;
    const int n0 = blk * 4;
    const long e0 = (long)blk * 64;

    // ---------------- stage ----------------
    if (tid < 64)  s_cut[tid] = cutoff[e0 + tid];
    if (tid < 256) s_q[tid] = node_feat[(long)(n0 + (tid >> 6)) * 64 + (tid & 63)];
    s_wl[tid] = Wlogit[tid];
    s_sh[tid] = edge_sh[e0 * 8 + tid];
    { int row = tid >> 3, part = tid & 7;
      const float4* src = (const float4*)(edge_inv + (e0 + row) * 64) + part * 2;
      u16x4* dst = (u16x4*)(s_inv + row * 72 + part * 8);
      dst[0] = pack4(src[0]); dst[1] = pack4(src[1]);
      int sr = edge_src[e0 + row];
      const float4* sx = (const float4*)(node_feat + (long)sr * 64) + part * 2;
      u16x4* dx = (u16x4*)(s_x + row * 72 + part * 8);
      dx[0] = pack4(sx[0]); dx[1] = pack4(sx[1]);
    }
    __syncthreads();

    // ---------------- layer 1 (k & v in parallel across waves) ----------------
    const int mat = w >> 2, ct12 = w & 3;
    mlp_layer(wsw + (mat ? WS_WV1 : WS_WK1), s_inv, s_h1 + mat * 4608, ct12, lane, 0, 4);
    __syncthreads();

    // ---------------- layer 2 (k only, all 8 waves: 4 ct x 2 et-halves) ----------------
    const int eh = w >> 2;
    mlp_layer(wsw + WS_WK2, s_h1, s_h2, ct12, lane, eh * 2, eh * 2 + 2);
    __syncthreads();

    // ---------------- layer 3 k-path + logits ----------------
    {
        bf16x8 ak0[5], ak1[5];
#pragma unroll
        for (int ci = 0; ci < 5; ++ci) {
            int ct = w + 8 * ci;
            if (ct < 36) {
                const u16* Af = wsw + WS_WK3 + ct * 1024 + lane * 8;
                ak0[ci] = *(const bf16x8*)(Af);
                ak1[ci] = *(const bf16x8*)(Af + 512);
            }
        }
#pragma unroll
        for (int et = 0; et < 4; ++et) {
            const u16* br = s_h2 + (et * 16 + el) * 72 + q4 * 8;
            bf16x8 b0 = *(const bf16x8*)(br);
            bf16x8 b1 = *(const bf16x8*)(br + 32);
            float L0 = 0.f, L1 = 0.f, L2 = 0.f, L3 = 0.f;
#pragma unroll
            for (int ci = 0; ci < 5; ++ci) {
                int ct = w + 8 * ci;
                if (ct < 36) {
                    f32x4 c = {0.f, 0.f, 0.f, 0.f};
                    c = MFMA(ak0[ci], b0, c);
                    c = MFMA(ak1[ci], b1, c);
                    if (ct < 4) {
                        const float* qp = s_q + et * 64 + ct * 16 + 4 * q4;
                        u16x4 xv = *(const u16x4*)(s_x + (et * 16 + el) * 72 + ct * 16 + 4 * q4);
#pragma unroll
                        for (int r = 0; r < 4; ++r) {
                            const float* wlp = s_wl + (ct * 16 + 4 * q4 + r) * 4;
                            float wk = c[r] * qp[r] * b2f(xv[r]);
                            L0 += wk * wlp[0]; L1 += wk * wlp[1];
                            L2 += wk * wlp[2]; L3 += wk * wlp[3];
                        }
                    } else {
                        int dd = 2 * (ct - 4) + (q4 >> 1), sb = (q4 & 1) * 4;
                        float qd = s_q[et * 64 + dd];
                        float xd = b2f(s_x[(et * 16 + el) * 72 + dd]);
                        float4 sp = *(const float4*)(s_sh + (et * 16 + el) * 8 + sb);
                        float ss = c[0]*sp.x*sp.x + c[1]*sp.y*sp.y + c[2]*sp.z*sp.z + c[3]*sp.w*sp.w;
                        float wk = ss * qd * xd;
                        const float* wlp = s_wl + (64 + dd) * 4;
                        L0 += wk * wlp[0]; L1 += wk * wlp[1];
                        L2 += wk * wlp[2]; L3 += wk * wlp[3];
                    }
                }
            }
            L0 += __shfl_xor(L0, 16, 64); L0 += __shfl_xor(L0, 32, 64);
            L1 += __shfl_xor(L1, 16, 64); L1 += __shfl_xor(L1, 32, 64);
            L2 += __shfl_xor(L2, 16, 64); L2 += __shfl_xor(L2, 32, 64);
            L3 += __shfl_xor(L3, 16, 64); L3 += __shfl_xor(L3, 32, 64);
            if (lane < 16) {
                float* p = s_lp + w * 256 + (et * 16 + lane) * 4;
                p[0] = L0; p[1] = L1; p[2] = L2; p[3] = L3;
            }
        }
    }
    __syncthreads();

    // -------- softmax (wave 0) concurrent with layer 2 (v, all waves) --------
    if (w == 0) {
        float l4[4] = {0.f, 0.f, 0.f, 0.f};
#pragma unroll
        for (int ww = 0; ww < 8; ++ww) {
            float4 p = *(const float4*)(s_lp + ww * 256 + lane * 4);
            l4[0] += p.x; l4[1] += p.y; l4[2] += p.z; l4[3] += p.w;
        }
        float cut = s_cut[lane];
        float wg[4];
#pragma unroll
        for (int h = 0; h < 4; ++h) {
            float m = l4[h];
            m = fmaxf(m, __shfl_xor(m, 1, 64));
            m = fmaxf(m, __shfl_xor(m, 2, 64));
            m = fmaxf(m, __shfl_xor(m, 4, 64));
            m = fmaxf(m, __shfl_xor(m, 8, 64));
            float ex = cut * __expf(l4[h] - m);
            float z = ex;
            z += __shfl_xor(z, 1, 64);
            z += __shfl_xor(z, 2, 64);
            z += __shfl_xor(z, 4, 64);
            z += __shfl_xor(z, 8, 64);
            if (z == 0.f) z = 1.f;
            float a = __fdividef(ex, z);
            wg[h] = sqrtf(fmaxf(a, 0.f));
        }
        float4 o; o.x = wg[0]; o.y = wg[1]; o.z = wg[2]; o.w = wg[3];
        *(float4*)(s_wgt + lane * 4) = o;
    }
    mlp_layer(wsw + WS_WV2, s_h1 + 4608, s_h2, ct12, lane, eh * 2, eh * 2 + 2);
    __syncthreads();

    // ---- layer 3 v-path + weighting + per-edge Wout projection (MFMA K=16) ----
    {
        bf16x8 av0[5], av1[5];
#pragma unroll
        for (int ci = 0; ci < 5; ++ci) {
            int ct = w + 8 * ci;
            if (ct < 36) {
                const u16* Af = wsw + WS_WV3 + ct * 1024 + lane * 8;
                av0[ci] = *(const bf16x8*)(Af);
                av1[ci] = *(const bf16x8*)(Af + 512);
            }
        }
#pragma unroll
        for (int et = 0; et < 4; ++et) {
            const u16* br = s_h2 + (et * 16 + el) * 72 + q4 * 8;
            bf16x8 b0 = *(const bf16x8*)(br);
            bf16x8 b1 = *(const bf16x8*)(br + 32);
            float4 wg4 = *(const float4*)(s_wgt + (et * 16 + el) * 4);
            f32x4 accj[4];
#pragma unroll
            for (int jt = 0; jt < 4; ++jt) accj[jt] = (f32x4){0.f, 0.f, 0.f, 0.f};
#pragma unroll
            for (int ci = 0; ci < 5; ++ci) {
                int ct = w + 8 * ci;
                if (ct < 36) {
                    f32x4 c = {0.f, 0.f, 0.f, 0.f};
                    c = MFMA(av0[ci], b0, c);
                    c = MFMA(av1[ci], b1, c);
                    int c0q = ct * 16 + 4 * q4;
                    int h = (c0q >= 432) ? 3 : (c0q >= 288) ? 2 : (c0q >= 144) ? 1 : 0;
                    float wgt = (h == 0) ? wg4.x : (h == 1) ? wg4.y : (h == 2) ? wg4.z : wg4.w;
                    float v0, v1, v2, v3;
                    if (ct < 4) {
                        u16x4 xv = *(const u16x4*)(s_x + (et * 16 + el) * 72 + c0q);
                        v0 = c[0] * b2f(xv[0]) * wgt;
                        v1 = c[1] * b2f(xv[1]) * wgt;
                        v2 = c[2] * b2f(xv[2]) * wgt;
                        v3 = c[3] * b2f(xv[3]) * wgt;
                    } else {
                        int dd = 2 * (ct - 4) + (q4 >> 1), sb = (q4 & 1) * 4;
                        float xd = b2f(s_x[(et * 16 + el) * 72 + dd]) * wgt;
                        float4 shp = *(const float4*)(s_sh + (et * 16 + el) * 8 + sb);
                        v0 = c[0] * xd * shp.x;
                        v1 = c[1] * xd * shp.y;
                        v2 = c[2] * xd * shp.z;
                        v3 = c[3] * xd * shp.w;
                    }
                    // weighted values: A-frag layout for K=16 MFMA (m=edge el, k=4q4+r)
                    unsigned long long uu =
                        ((unsigned long long)f2b2(v2, v3) << 32) | f2b2(v0, v1);
                    bf16x4 aw; __builtin_memcpy(&aw, &uu, 8);
#pragma unroll
                    for (int jt = 0; jt < 4; ++jt) {
                        bf16x4 bw = *(const bf16x4*)(wsw + WS_WO + (size_t)(ct * 4 + jt) * 256 + lane * 4);
                        accj[jt] = MFMA16(aw, bw, accj[jt]);
                    }
                }
            }
            // D[m=edge 4q4+r][n=j jt*16+el]: sum own 4 edges, then cross-q4 -> node sum
#pragma unroll
            for (int jt = 0; jt < 4; ++jt) {
                float s = accj[jt][0] + accj[jt][1] + accj[jt][2] + accj[jt][3];
                s += __shfl_xor(s, 16, 64);
                s += __shfl_xor(s, 32, 64);
                if (q4 == 0) s_yp[(w * 4 + et) * 64 + jt * 16 + el] = s;
            }
        }
    }
    __syncthreads();

    // ---------------- final: sum the 8 wave partials per node ----------------
    if (tid < 256) {
        int et = tid >> 6, j = tid & 63;
        float r = 0.f;
#pragma unroll
        for (int ww = 0; ww < 8; ++ww) r += s_yp[(ww * 4 + et) * 64 + j];
        out[(long)(n0 + et) * 64 + j] = r;
    }
}

extern "C" void kernel_launch(void* const* d_in, const int* in_sizes, int n_in,
                              void* d_out, int out_size, void* d_ws, size_t ws_size,
                              hipStream_t stream) {
    const float* node_feat = (const float*)d_in[0];
    const float* edge_sh   = (const float*)d_in[1];
    const float* edge_inv  = (const float*)d_in[2];
    const float* cutoff    = (const float*)d_in[3];
    const float* Wk1       = (const float*)d_in[4];
    const float* Wk2       = (const float*)d_in[5];
    const float* Wk3       = (const float*)d_in[6];
    const float* Wv1       = (const float*)d_in[7];
    const float* Wv2       = (const float*)d_in[8];
    const float* Wv3       = (const float*)d_in[9];
    const float* Wlogit    = (const float*)d_in[10];
    const float* Wout      = (const float*)d_in[11];
    const int*   edge_src  = (const int*)d_in[12];
    float* out = (float*)d_out;
    u16* wsw = (u16*)d_ws;

    prep<<<(WS_TOTAL + 255) / 256, 256, 0, stream>>>(
        Wk1, Wk2, Wk3, Wv1, Wv2, Wv3, Wout, wsw);
    fused<<<2048, 512, 0, stream>>>(
        node_feat, edge_sh, edge_inv, cutoff, Wlogit, edge_src, wsw, out);
}

// Round 10
// 175.540 us; speedup vs baseline: 1.2352x; 1.1661x over previous
//
#include <hip/hip_runtime.h>
#include <math.h>

typedef unsigned short u16;
typedef short bf16x8 __attribute__((ext_vector_type(8)));
typedef short bf16x4 __attribute__((ext_vector_type(4)));
typedef unsigned short u16x4 __attribute__((ext_vector_type(4)));
typedef float f32x4 __attribute__((ext_vector_type(4)));

#define MFMA(a,b,c)   __builtin_amdgcn_mfma_f32_16x16x32_bf16((a),(b),(c),0,0,0)
#define MFMA16(a,b,c) __builtin_amdgcn_mfma_f32_16x16x16bf16_1k((a),(b),(c),0,0,0)

// ws layout (u16 elements): pre-swizzled bf16 MFMA A/B fragments
#define WS_WK1 0
#define WS_WV1 8192
#define WS_WK2 16384
#define WS_WV2 24576
#define WS_WK3 32768
#define WS_WV3 69632
#define WS_WO  106496      // 144 frags (ct 36 x jt 4) x 256 u16, B-layout K=16
#define WS_TOTAL 143360

// LDS byte offsets (64 edges / 4 nodes per block) — total 52480 B
#define OFF_H1   0        // [2][64][72] u16 = 18432  (overlay: s_yp [8][4][64] f32)
#define OFF_H2   18432    // [64][72] u16 = 9216 (single buffer, k then v)
#define OFF_INV  27648    // [64][72] u16 = 9216      (overlay: s_lp [8][64][4] f32)
#define OFF_X    36864    // [64][72] u16 = 9216
#define OFF_SH   46080    // [64][8] f32 = 2048
#define OFF_Q    48128    // [4][64] f32 = 1024
#define OFF_CUT  49152    // [64] f32 = 256
#define OFF_WL   49408    // [128][4] f32 = 2048
#define OFF_WGT  51456    // [64][4] f32 = 1024
#define SMEM_SZ  52480

__device__ __forceinline__ u16 f2b(float f) {
    unsigned int u; __builtin_memcpy(&u, &f, 4);
    u += 0x7FFFu + ((u >> 16) & 1u);          // round-to-nearest-even
    return (u16)(u >> 16);
}
__device__ __forceinline__ float b2f(u16 v) {
    unsigned int u = ((unsigned int)v) << 16;
    float f; __builtin_memcpy(&f, &u, 4);
    return f;
}
__device__ __forceinline__ u16x4 pack4(float4 v) {
    u16x4 o; o.x = f2b(v.x); o.y = f2b(v.y); o.z = f2b(v.z); o.w = f2b(v.w);
    return o;
}
__device__ __forceinline__ float gelu(float x) {
    float u = 0.7978845608028654f * x * (1.0f + 0.044715f * x * x);
    u = fminf(fmaxf(u, -15.0f), 15.0f);
    float e = __expf(2.0f * u);
    float t = __fdividef(e - 1.0f, e + 1.0f);  // tanh(u)
    return 0.5f * x * (1.0f + t);
}

// ---------------- weight pre-swizzle: fp32 [K x N] -> bf16 MFMA frags ----------------
__global__ void prep(const float* __restrict__ Wk1, const float* __restrict__ Wk2,
                     const float* __restrict__ Wk3, const float* __restrict__ Wv1,
                     const float* __restrict__ Wv2, const float* __restrict__ Wv3,
                     const float* __restrict__ Wout, u16* __restrict__ wsw) {
    int i = blockIdx.x * 256 + threadIdx.x;
    if (i >= WS_TOTAL) return;
    if (i >= WS_WO) {
        // Wout as B-operand frags for v_mfma_f32_16x16x16_bf16:
        // frag f = ct*4+jt; lane l holds B[n=j][k=c]: n=jt*16+(l&15), k=ct*16+(l>>4)*4+j4
        int pos = i - WS_WO;
        int f = pos >> 8, idx = pos & 255;
        int l = idx >> 2, j4 = idx & 3;
        int ct = f >> 2, jt = f & 3;
        int c = ct * 16 + ((l >> 4) << 2) + j4;
        int j = jt * 16 + (l & 15);
        wsw[i] = f2b(Wout[c * 64 + j]);
        return;
    }
    const float* W; int Kd, Nd, pos;
    if      (i < WS_WV1) { W = Wk1;  Kd = 64;  Nd = 64;  pos = i; }
    else if (i < WS_WK2) { W = Wv1;  Kd = 64;  Nd = 64;  pos = i - WS_WV1; }
    else if (i < WS_WV2) { W = Wk2;  Kd = 64;  Nd = 64;  pos = i - WS_WK2; }
    else if (i < WS_WK3) { W = Wv2;  Kd = 64;  Nd = 64;  pos = i - WS_WV2; }
    else if (i < WS_WV3) { W = Wk3;  Kd = 64;  Nd = 576; pos = i - WS_WK3; }
    else                 { W = Wv3;  Kd = 64;  Nd = 576; pos = i - WS_WV3; }
    int f = pos >> 9, rr = pos & 511, l = rr >> 3, j = rr & 7;
    int ktN = Kd >> 5;
    int mt = f / ktN, kt = f - mt * ktN;
    int m = mt * 16 + (l & 15);
    int k = kt * 32 + ((l >> 4) << 3) + j;
    wsw[i] = f2b(W[k * Nd + m]);
}

// one (ct, et-range) task: D[16ch x 16e] tiles = W^T*act, gelu, store [e][ch] bf16
__device__ __forceinline__ void mlp_layer(const u16* __restrict__ Wf,
                                          const u16* __restrict__ sin,
                                          u16* __restrict__ sout,
                                          int ct, int lane, int et0, int et1) {
    const int q = lane >> 4, el = lane & 15;
    bf16x8 a0 = *(const bf16x8*)(Wf + (ct * 2 + 0) * 512 + lane * 8);
    bf16x8 a1 = *(const bf16x8*)(Wf + (ct * 2 + 1) * 512 + lane * 8);
    for (int et = et0; et < et1; ++et) {
        const u16* br = sin + (et * 16 + el) * 72 + q * 8;
        bf16x8 b0 = *(const bf16x8*)(br);
        bf16x8 b1 = *(const bf16x8*)(br + 32);
        f32x4 c = {0.f, 0.f, 0.f, 0.f};
        c = MFMA(a0, b0, c);
        c = MFMA(a1, b1, c);
        u16x4 o;
        o.x = f2b(gelu(c[0])); o.y = f2b(gelu(c[1]));
        o.z = f2b(gelu(c[2])); o.w = f2b(gelu(c[3]));
        *(u16x4*)(sout + (et * 16 + el) * 72 + ct * 16 + q * 4) = o;
    }
}

__global__ __launch_bounds__(512, 4) void fused(
    const float* __restrict__ node_feat, const float* __restrict__ edge_sh,
    const float* __restrict__ edge_inv, const float* __restrict__ cutoff,
    const float* __restrict__ Wlogit, const int* __restrict__ edge_src,
    const u16* __restrict__ wsw, float* __restrict__ out)
{
    __shared__ __align__(16) unsigned char smem[SMEM_SZ];
    u16*   s_h1  = (u16*)(smem + OFF_H1);     // [2][64][72]
    u16*   s_h2  = (u16*)(smem + OFF_H2);     // [64][72] (k then v)
    u16*   s_inv = (u16*)(smem + OFF_INV);    // [64][72]
    u16*   s_x   = (u16*)(smem + OFF_X);      // [64][72]
    float* s_sh  = (float*)(smem + OFF_SH);   // [64][8]
    float* s_q   = (float*)(smem + OFF_Q);    // [4][64]
    float* s_cut = (float*)(smem + OFF_CUT);  // [64]
    float* s_wl  = (float*)(smem + OFF_WL);   // [128][4]
    float* s_wgt = (float*)(smem + OFF_WGT);  // [64][4]
    float* s_lp  = (float*)(smem + OFF_INV);  // overlay (inv dead after L1): [8][64][4]
    float* s_yp  = (float*)(smem + OFF_H1);   // overlay (h1k dead after L2k): [8][4][64]

    const int tid = threadIdx.x;
    const int lane = tid & 63;
    const int w = tid >> 6;
    const int q4 = lane >> 4;     // quad
    const int el = lane & 15;
    const int blk = blockIdx.x;
    const int n0 = blk * 4;
    const long e0 = (long)blk * 64;

    // ---------------- stage ----------------
    if (tid < 64)  s_cut[tid] = cutoff[e0 + tid];
    if (tid < 256) s_q[tid] = node_feat[(long)(n0 + (tid >> 6)) * 64 + (tid & 63)];
    s_wl[tid] = Wlogit[tid];
    s_sh[tid] = edge_sh[e0 * 8 + tid];
    { int row = tid >> 3, part = tid & 7;
      const float4* src = (const float4*)(edge_inv + (e0 + row) * 64) + part * 2;
      u16x4* dst = (u16x4*)(s_inv + row * 72 + part * 8);
      dst[0] = pack4(src[0]); dst[1] = pack4(src[1]);
      int sr = edge_src[e0 + row];
      const float4* sx = (const float4*)(node_feat + (long)sr * 64) + part * 2;
      u16x4* dx = (u16x4*)(s_x + row * 72 + part * 8);
      dx[0] = pack4(sx[0]); dx[1] = pack4(sx[1]);
    }
    __syncthreads();

    // ---------------- layer 1 (k & v in parallel across waves) ----------------
    const int mat = w >> 2, ct12 = w & 3;
    mlp_layer(wsw + (mat ? WS_WV1 : WS_WK1), s_inv, s_h1 + mat * 4608, ct12, lane, 0, 4);
    __syncthreads();

    // ---------------- layer 2 (k only, all 8 waves: 4 ct x 2 et-halves) ----------------
    const int eh = w >> 2;
    mlp_layer(wsw + WS_WK2, s_h1, s_h2, ct12, lane, eh * 2, eh * 2 + 2);
    __syncthreads();

    // ---------------- layer 3 k-path + logits ----------------
    {
        bf16x8 ak0[5], ak1[5];
#pragma unroll
        for (int ci = 0; ci < 5; ++ci) {
            int ct = w + 8 * ci;
            if (ct < 36) {
                const u16* Af = wsw + WS_WK3 + ct * 1024 + lane * 8;
                ak0[ci] = *(const bf16x8*)(Af);
                ak1[ci] = *(const bf16x8*)(Af + 512);
            }
        }
        // unroll 1: one et in flight — keeps live set under the 64-VGPR budget
#pragma unroll 1
        for (int et = 0; et < 4; ++et) {
            const u16* br = s_h2 + (et * 16 + el) * 72 + q4 * 8;
            bf16x8 b0 = *(const bf16x8*)(br);
            bf16x8 b1 = *(const bf16x8*)(br + 32);
            float L0 = 0.f, L1 = 0.f, L2 = 0.f, L3 = 0.f;
#pragma unroll
            for (int ci = 0; ci < 5; ++ci) {
                int ct = w + 8 * ci;
                if (ct < 36) {
                    f32x4 c = {0.f, 0.f, 0.f, 0.f};
                    c = MFMA(ak0[ci], b0, c);
                    c = MFMA(ak1[ci], b1, c);
                    if (ct < 4) {
                        const float* qp = s_q + et * 64 + ct * 16 + 4 * q4;
                        u16x4 xv = *(const u16x4*)(s_x + (et * 16 + el) * 72 + ct * 16 + 4 * q4);
#pragma unroll
                        for (int r = 0; r < 4; ++r) {
                            const float* wlp = s_wl + (ct * 16 + 4 * q4 + r) * 4;
                            float wk = c[r] * qp[r] * b2f(xv[r]);
                            L0 += wk * wlp[0]; L1 += wk * wlp[1];
                            L2 += wk * wlp[2]; L3 += wk * wlp[3];
                        }
                    } else {
                        int dd = 2 * (ct - 4) + (q4 >> 1), sb = (q4 & 1) * 4;
                        float qd = s_q[et * 64 + dd];
                        float xd = b2f(s_x[(et * 16 + el) * 72 + dd]);
                        float4 sp = *(const float4*)(s_sh + (et * 16 + el) * 8 + sb);
                        float ss = c[0]*sp.x*sp.x + c[1]*sp.y*sp.y + c[2]*sp.z*sp.z + c[3]*sp.w*sp.w;
                        float wk = ss * qd * xd;
                        const float* wlp = s_wl + (64 + dd) * 4;
                        L0 += wk * wlp[0]; L1 += wk * wlp[1];
                        L2 += wk * wlp[2]; L3 += wk * wlp[3];
                    }
                }
            }
            L0 += __shfl_xor(L0, 16, 64); L0 += __shfl_xor(L0, 32, 64);
            L1 += __shfl_xor(L1, 16, 64); L1 += __shfl_xor(L1, 32, 64);
            L2 += __shfl_xor(L2, 16, 64); L2 += __shfl_xor(L2, 32, 64);
            L3 += __shfl_xor(L3, 16, 64); L3 += __shfl_xor(L3, 32, 64);
            if (lane < 16) {
                float* p = s_lp + w * 256 + (et * 16 + lane) * 4;
                p[0] = L0; p[1] = L1; p[2] = L2; p[3] = L3;
            }
        }
    }
    __syncthreads();

    // -------- softmax (wave 0) concurrent with layer 2 (v, all waves) --------
    if (w == 0) {
        float l4[4] = {0.f, 0.f, 0.f, 0.f};
#pragma unroll
        for (int ww = 0; ww < 8; ++ww) {
            float4 p = *(const float4*)(s_lp + ww * 256 + lane * 4);
            l4[0] += p.x; l4[1] += p.y; l4[2] += p.z; l4[3] += p.w;
        }
        float cut = s_cut[lane];
        float wg[4];
#pragma unroll
        for (int h = 0; h < 4; ++h) {
            float m = l4[h];
            m = fmaxf(m, __shfl_xor(m, 1, 64));
            m = fmaxf(m, __shfl_xor(m, 2, 64));
            m = fmaxf(m, __shfl_xor(m, 4, 64));
            m = fmaxf(m, __shfl_xor(m, 8, 64));
            float ex = cut * __expf(l4[h] - m);
            float z = ex;
            z += __shfl_xor(z, 1, 64);
            z += __shfl_xor(z, 2, 64);
            z += __shfl_xor(z, 4, 64);
            z += __shfl_xor(z, 8, 64);
            if (z == 0.f) z = 1.f;
            float a = __fdividef(ex, z);
            wg[h] = sqrtf(fmaxf(a, 0.f));
        }
        float4 o; o.x = wg[0]; o.y = wg[1]; o.z = wg[2]; o.w = wg[3];
        *(float4*)(s_wgt + lane * 4) = o;
    }
    mlp_layer(wsw + WS_WV2, s_h1 + 4608, s_h2, ct12, lane, eh * 2, eh * 2 + 2);
    __syncthreads();

    // ---- layer 3 v-path + weighting + per-edge Wout projection (MFMA K=16) ----
    {
        bf16x8 av0[5], av1[5];
#pragma unroll
        for (int ci = 0; ci < 5; ++ci) {
            int ct = w + 8 * ci;
            if (ct < 36) {
                const u16* Af = wsw + WS_WV3 + ct * 1024 + lane * 8;
                av0[ci] = *(const bf16x8*)(Af);
                av1[ci] = *(const bf16x8*)(Af + 512);
            }
        }
        // unroll 1: one et in flight — spill-avoidance (see R9 post-mortem)
#pragma unroll 1
        for (int et = 0; et < 4; ++et) {
            const u16* br = s_h2 + (et * 16 + el) * 72 + q4 * 8;
            bf16x8 b0 = *(const bf16x8*)(br);
            bf16x8 b1 = *(const bf16x8*)(br + 32);
            float4 wg4 = *(const float4*)(s_wgt + (et * 16 + el) * 4);
            f32x4 accj[4];
#pragma unroll
            for (int jt = 0; jt < 4; ++jt) accj[jt] = (f32x4){0.f, 0.f, 0.f, 0.f};
#pragma unroll
            for (int ci = 0; ci < 5; ++ci) {
                int ct = w + 8 * ci;
                if (ct < 36) {
                    f32x4 c = {0.f, 0.f, 0.f, 0.f};
                    c = MFMA(av0[ci], b0, c);
                    c = MFMA(av1[ci], b1, c);
                    int c0q = ct * 16 + 4 * q4;
                    int h = (c0q >= 432) ? 3 : (c0q >= 288) ? 2 : (c0q >= 144) ? 1 : 0;
                    float wgt = (h == 0) ? wg4.x : (h == 1) ? wg4.y : (h == 2) ? wg4.z : wg4.w;
                    float v0, v1, v2, v3;
                    if (ct < 4) {
                        u16x4 xv = *(const u16x4*)(s_x + (et * 16 + el) * 72 + c0q);
                        v0 = c[0] * b2f(xv[0]) * wgt;
                        v1 = c[1] * b2f(xv[1]) * wgt;
                        v2 = c[2] * b2f(xv[2]) * wgt;
                        v3 = c[3] * b2f(xv[3]) * wgt;
                    } else {
                        int dd = 2 * (ct - 4) + (q4 >> 1), sb = (q4 & 1) * 4;
                        float xd = b2f(s_x[(et * 16 + el) * 72 + dd]) * wgt;
                        float4 shp = *(const float4*)(s_sh + (et * 16 + el) * 8 + sb);
                        v0 = c[0] * xd * shp.x;
                        v1 = c[1] * xd * shp.y;
                        v2 = c[2] * xd * shp.z;
                        v3 = c[3] * xd * shp.w;
                    }
                    // weighted values: A-frag layout for K=16 MFMA (m=edge el, k=4q4+r)
                    bf16x4 aw;
                    aw.x = (short)f2b(v0); aw.y = (short)f2b(v1);
                    aw.z = (short)f2b(v2); aw.w = (short)f2b(v3);
#pragma unroll
                    for (int jt = 0; jt < 4; ++jt) {
                        bf16x4 bw = *(const bf16x4*)(wsw + WS_WO + (size_t)(ct * 4 + jt) * 256 + lane * 4);
                        accj[jt] = MFMA16(aw, bw, accj[jt]);
                    }
                }
            }
            // D[m=edge 4q4+r][n=j jt*16+el]: sum own 4 edges, then cross-q4 -> node sum
#pragma unroll
            for (int jt = 0; jt < 4; ++jt) {
                float s = accj[jt][0] + accj[jt][1] + accj[jt][2] + accj[jt][3];
                s += __shfl_xor(s, 16, 64);
                s += __shfl_xor(s, 32, 64);
                if (q4 == 0) s_yp[(w * 4 + et) * 64 + jt * 16 + el] = s;
            }
        }
    }
    __syncthreads();

    // ---------------- final: sum the 8 wave partials per node ----------------
    if (tid < 256) {
        int et = tid >> 6, j = tid & 63;
        float r = 0.f;
#pragma unroll
        for (int ww = 0; ww < 8; ++ww) r += s_yp[(ww * 4 + et) * 64 + j];
        out[(long)(n0 + et) * 64 + j] = r;
    }
}

extern "C" void kernel_launch(void* const* d_in, const int* in_sizes, int n_in,
                              void* d_out, int out_size, void* d_ws, size_t ws_size,
                              hipStream_t stream) {
    const float* node_feat = (const float*)d_in[0];
    const float* edge_sh   = (const float*)d_in[1];
    const float* edge_inv  = (const float*)d_in[2];
    const float* cutoff    = (const float*)d_in[3];
    const float* Wk1       = (const float*)d_in[4];
    const float* Wk2       = (const float*)d_in[5];
    const float* Wk3       = (const float*)d_in[6];
    const float* Wv1       = (const float*)d_in[7];
    const float* Wv2       = (const float*)d_in[8];
    const float* Wv3       = (const float*)d_in[9];
    const float* Wlogit    = (const float*)d_in[10];
    const float* Wout      = (const float*)d_in[11];
    const int*   edge_src  = (const int*)d_in[12];
    float* out = (float*)d_out;
    u16* wsw = (u16*)d_ws;

    prep<<<(WS_TOTAL + 255) / 256, 256, 0, stream>>>(
        Wk1, Wk2, Wk3, Wv1, Wv2, Wv3, Wout, wsw);
    fused<<<2048, 512, 0, stream>>>(
        node_feat, edge_sh, edge_inv, cutoff, Wlogit, edge_src, wsw, out);
}

// Round 11
// 169.928 us; speedup vs baseline: 1.2760x; 1.0330x over previous
//
#include <hip/hip_runtime.h>
#include <math.h>

typedef unsigned short u16;
typedef short bf16x8 __attribute__((ext_vector_type(8)));
typedef short bf16x4 __attribute__((ext_vector_type(4)));
typedef unsigned short u16x4 __attribute__((ext_vector_type(4)));
typedef float f32x4 __attribute__((ext_vector_type(4)));

#define MFMA(a,b,c)   __builtin_amdgcn_mfma_f32_16x16x32_bf16((a),(b),(c),0,0,0)
#define MFMA16(a,b,c) __builtin_amdgcn_mfma_f32_16x16x16bf16_1k((a),(b),(c),0,0,0)

// ws layout (u16 elements): pre-swizzled bf16 MFMA A/B fragments
#define WS_WK1 0
#define WS_WV1 8192
#define WS_WK2 16384
#define WS_WV2 24576
#define WS_WK3 32768
#define WS_WV3 69632
#define WS_WO  106496      // 144 frags (ct 36 x jt 4) x 256 u16, B-layout K=16
#define WS_TOTAL 143360

// LDS byte offsets (64 edges / 4 nodes per block) — total 52480 B
#define OFF_H1   0        // [2][64][72] u16 = 18432  (overlay: s_yp [8][4][64] f32)
#define OFF_H2   18432    // [64][72] u16 = 9216 (single buffer, k then v)
#define OFF_INV  27648    // [64][72] u16 = 9216      (overlay: s_lp [8][64][4] f32)
#define OFF_X    36864    // [64][72] u16 = 9216
#define OFF_SH   46080    // [64][8] f32 = 2048
#define OFF_Q    48128    // [4][64] f32 = 1024
#define OFF_CUT  49152    // [64] f32 = 256
#define OFF_WL   49408    // [128][4] f32 = 2048
#define OFF_WGT  51456    // [64][4] f32 = 1024
#define SMEM_SZ  52480

__device__ __forceinline__ u16 f2b(float f) {
    unsigned int u; __builtin_memcpy(&u, &f, 4);
    u += 0x7FFFu + ((u >> 16) & 1u);          // round-to-nearest-even
    return (u16)(u >> 16);
}
__device__ __forceinline__ float b2f(u16 v) {
    unsigned int u = ((unsigned int)v) << 16;
    float f; __builtin_memcpy(&f, &u, 4);
    return f;
}
__device__ __forceinline__ u16x4 pack4(float4 v) {
    u16x4 o; o.x = f2b(v.x); o.y = f2b(v.y); o.z = f2b(v.z); o.w = f2b(v.w);
    return o;
}
// gelu(tanh form) rearranged: 0.5x(1+tanh(u)) == x * sigmoid(2u) == x / (1 + e^{-2u})
// with u = c0*(x + c1 x^3) = c0*x*(1 + c1 x^2).  exp(-2u) = 2^(K*x*(1+c1 x^2)),
// K = -2*c0*log2(e).  8 VALU ops, no clamps needed (e->0 => x; e->inf => 0).
__device__ __forceinline__ float gelu(float x) {
    const float c1 = 0.044715f;
    const float K  = -2.0f * 0.7978845608028654f * 1.4426950408889634f;
    float t  = x * x;
    float t2 = fmaf(c1, t, 1.0f);
    float p  = (K * x) * t2;
    float e  = __builtin_amdgcn_exp2f(p);
    float r  = __builtin_amdgcn_rcpf(1.0f + e);
    return x * r;
}

// ---------------- weight pre-swizzle: fp32 [K x N] -> bf16 MFMA frags ----------------
__global__ void prep(const float* __restrict__ Wk1, const float* __restrict__ Wk2,
                     const float* __restrict__ Wk3, const float* __restrict__ Wv1,
                     const float* __restrict__ Wv2, const float* __restrict__ Wv3,
                     const float* __restrict__ Wout, u16* __restrict__ wsw) {
    int i = blockIdx.x * 256 + threadIdx.x;
    if (i >= WS_TOTAL) return;
    if (i >= WS_WO) {
        // Wout as B-operand frags for v_mfma_f32_16x16x16_bf16:
        // frag f = ct*4+jt; lane l holds B[n=j][k=c]: n=jt*16+(l&15), k=ct*16+(l>>4)*4+j4
        int pos = i - WS_WO;
        int f = pos >> 8, idx = pos & 255;
        int l = idx >> 2, j4 = idx & 3;
        int ct = f >> 2, jt = f & 3;
        int c = ct * 16 + ((l >> 4) << 2) + j4;
        int j = jt * 16 + (l & 15);
        wsw[i] = f2b(Wout[c * 64 + j]);
        return;
    }
    const float* W; int Kd, Nd, pos;
    if      (i < WS_WV1) { W = Wk1;  Kd = 64;  Nd = 64;  pos = i; }
    else if (i < WS_WK2) { W = Wv1;  Kd = 64;  Nd = 64;  pos = i - WS_WV1; }
    else if (i < WS_WV2) { W = Wk2;  Kd = 64;  Nd = 64;  pos = i - WS_WK2; }
    else if (i < WS_WK3) { W = Wv2;  Kd = 64;  Nd = 64;  pos = i - WS_WV2; }
    else if (i < WS_WV3) { W = Wk3;  Kd = 64;  Nd = 576; pos = i - WS_WK3; }
    else                 { W = Wv3;  Kd = 64;  Nd = 576; pos = i - WS_WV3; }
    int f = pos >> 9, rr = pos & 511, l = rr >> 3, j = rr & 7;
    int ktN = Kd >> 5;
    int mt = f / ktN, kt = f - mt * ktN;
    int m = mt * 16 + (l & 15);
    int k = kt * 32 + ((l >> 4) << 3) + j;
    wsw[i] = f2b(W[k * Nd + m]);
}

// one (ct, et-range) task: D[16ch x 16e] tiles = W^T*act, gelu, store [e][ch] bf16
__device__ __forceinline__ void mlp_layer(const u16* __restrict__ Wf,
                                          const u16* __restrict__ sin,
                                          u16* __restrict__ sout,
                                          int ct, int lane, int et0, int et1) {
    const int q = lane >> 4, el = lane & 15;
    bf16x8 a0 = *(const bf16x8*)(Wf + (ct * 2 + 0) * 512 + lane * 8);
    bf16x8 a1 = *(const bf16x8*)(Wf + (ct * 2 + 1) * 512 + lane * 8);
    for (int et = et0; et < et1; ++et) {
        const u16* br = sin + (et * 16 + el) * 72 + q * 8;
        bf16x8 b0 = *(const bf16x8*)(br);
        bf16x8 b1 = *(const bf16x8*)(br + 32);
        f32x4 c = {0.f, 0.f, 0.f, 0.f};
        c = MFMA(a0, b0, c);
        c = MFMA(a1, b1, c);
        u16x4 o;
        o.x = f2b(gelu(c[0])); o.y = f2b(gelu(c[1]));
        o.z = f2b(gelu(c[2])); o.w = f2b(gelu(c[3]));
        *(u16x4*)(sout + (et * 16 + el) * 72 + ct * 16 + q * 4) = o;
    }
}

__global__ __launch_bounds__(512, 4) void fused(
    const float* __restrict__ node_feat, const float* __restrict__ edge_sh,
    const float* __restrict__ edge_inv, const float* __restrict__ cutoff,
    const float* __restrict__ Wlogit, const int* __restrict__ edge_src,
    const u16* __restrict__ wsw, float* __restrict__ out)
{
    __shared__ __align__(16) unsigned char smem[SMEM_SZ];
    u16*   s_h1  = (u16*)(smem + OFF_H1);     // [2][64][72]
    u16*   s_h2  = (u16*)(smem + OFF_H2);     // [64][72] (k then v)
    u16*   s_inv = (u16*)(smem + OFF_INV);    // [64][72]
    u16*   s_x   = (u16*)(smem + OFF_X);      // [64][72]
    float* s_sh  = (float*)(smem + OFF_SH);   // [64][8]
    float* s_q   = (float*)(smem + OFF_Q);    // [4][64]
    float* s_cut = (float*)(smem + OFF_CUT);  // [64]
    float* s_wl  = (float*)(smem + OFF_WL);   // [128][4]
    float* s_wgt = (float*)(smem + OFF_WGT);  // [64][4]
    float* s_lp  = (float*)(smem + OFF_INV);  // overlay (inv dead after L1): [8][64][4]
    float* s_yp  = (float*)(smem + OFF_H1);   // overlay (h1k dead after L2k): [8][4][64]

    const int tid = threadIdx.x;
    const int lane = tid & 63;
    const int w = tid >> 6;
    const int q4 = lane >> 4;     // quad
    const int el = lane & 15;
    const int blk = blockIdx.x;
    const int n0 = blk * 4;
    const long e0 = (long)blk * 64;

    // ---------------- stage ----------------
    if (tid < 64)  s_cut[tid] = cutoff[e0 + tid];
    if (tid < 256) s_q[tid] = node_feat[(long)(n0 + (tid >> 6)) * 64 + (tid & 63)];
    s_wl[tid] = Wlogit[tid];
    s_sh[tid] = edge_sh[e0 * 8 + tid];
    { int row = tid >> 3, part = tid & 7;
      const float4* src = (const float4*)(edge_inv + (e0 + row) * 64) + part * 2;
      u16x4* dst = (u16x4*)(s_inv + row * 72 + part * 8);
      dst[0] = pack4(src[0]); dst[1] = pack4(src[1]);
      int sr = edge_src[e0 + row];
      const float4* sx = (const float4*)(node_feat + (long)sr * 64) + part * 2;
      u16x4* dx = (u16x4*)(s_x + row * 72 + part * 8);
      dx[0] = pack4(sx[0]); dx[1] = pack4(sx[1]);
    }
    __syncthreads();

    // ---------------- layer 1 (k & v in parallel across waves) ----------------
    const int mat = w >> 2, ct12 = w & 3;
    mlp_layer(wsw + (mat ? WS_WV1 : WS_WK1), s_inv, s_h1 + mat * 4608, ct12, lane, 0, 4);
    __syncthreads();

    // ---------------- layer 2 (k only, all 8 waves: 4 ct x 2 et-halves) ----------------
    const int eh = w >> 2;
    mlp_layer(wsw + WS_WK2, s_h1, s_h2, ct12, lane, eh * 2, eh * 2 + 2);
    __syncthreads();

    // ---------------- layer 3 k-path + logits ----------------
    {
        bf16x8 ak0[5], ak1[5];
#pragma unroll
        for (int ci = 0; ci < 5; ++ci) {
            int ct = w + 8 * ci;
            if (ct < 36) {
                const u16* Af = wsw + WS_WK3 + ct * 1024 + lane * 8;
                ak0[ci] = *(const bf16x8*)(Af);
                ak1[ci] = *(const bf16x8*)(Af + 512);
            }
        }
        // unroll 1: one et in flight — keeps live set under the 64-VGPR budget
#pragma unroll 1
        for (int et = 0; et < 4; ++et) {
            const u16* br = s_h2 + (et * 16 + el) * 72 + q4 * 8;
            bf16x8 b0 = *(const bf16x8*)(br);
            bf16x8 b1 = *(const bf16x8*)(br + 32);
            float L0 = 0.f, L1 = 0.f, L2 = 0.f, L3 = 0.f;
#pragma unroll
            for (int ci = 0; ci < 5; ++ci) {
                int ct = w + 8 * ci;
                if (ct < 36) {
                    f32x4 c = {0.f, 0.f, 0.f, 0.f};
                    c = MFMA(ak0[ci], b0, c);
                    c = MFMA(ak1[ci], b1, c);
                    if (ct < 4) {
                        const float* qp = s_q + et * 64 + ct * 16 + 4 * q4;
                        u16x4 xv = *(const u16x4*)(s_x + (et * 16 + el) * 72 + ct * 16 + 4 * q4);
#pragma unroll
                        for (int r = 0; r < 4; ++r) {
                            const float* wlp = s_wl + (ct * 16 + 4 * q4 + r) * 4;
                            float wk = c[r] * qp[r] * b2f(xv[r]);
                            L0 += wk * wlp[0]; L1 += wk * wlp[1];
                            L2 += wk * wlp[2]; L3 += wk * wlp[3];
                        }
                    } else {
                        int dd = 2 * (ct - 4) + (q4 >> 1), sb = (q4 & 1) * 4;
                        float qd = s_q[et * 64 + dd];
                        float xd = b2f(s_x[(et * 16 + el) * 72 + dd]);
                        float4 sp = *(const float4*)(s_sh + (et * 16 + el) * 8 + sb);
                        float ss = c[0]*sp.x*sp.x + c[1]*sp.y*sp.y + c[2]*sp.z*sp.z + c[3]*sp.w*sp.w;
                        float wk = ss * qd * xd;
                        const float* wlp = s_wl + (64 + dd) * 4;
                        L0 += wk * wlp[0]; L1 += wk * wlp[1];
                        L2 += wk * wlp[2]; L3 += wk * wlp[3];
                    }
                }
            }
            L0 += __shfl_xor(L0, 16, 64); L0 += __shfl_xor(L0, 32, 64);
            L1 += __shfl_xor(L1, 16, 64); L1 += __shfl_xor(L1, 32, 64);
            L2 += __shfl_xor(L2, 16, 64); L2 += __shfl_xor(L2, 32, 64);
            L3 += __shfl_xor(L3, 16, 64); L3 += __shfl_xor(L3, 32, 64);
            if (lane < 16) {
                float* p = s_lp + w * 256 + (et * 16 + lane) * 4;
                p[0] = L0; p[1] = L1; p[2] = L2; p[3] = L3;
            }
        }
    }
    __syncthreads();

    // -------- softmax (wave 0) concurrent with layer 2 (v, all waves) --------
    if (w == 0) {
        float l4[4] = {0.f, 0.f, 0.f, 0.f};
#pragma unroll
        for (int ww = 0; ww < 8; ++ww) {
            float4 p = *(const float4*)(s_lp + ww * 256 + lane * 4);
            l4[0] += p.x; l4[1] += p.y; l4[2] += p.z; l4[3] += p.w;
        }
        float cut = s_cut[lane];
        float wg[4];
#pragma unroll
        for (int h = 0; h < 4; ++h) {
            float m = l4[h];
            m = fmaxf(m, __shfl_xor(m, 1, 64));
            m = fmaxf(m, __shfl_xor(m, 2, 64));
            m = fmaxf(m, __shfl_xor(m, 4, 64));
            m = fmaxf(m, __shfl_xor(m, 8, 64));
            float ex = cut * __expf(l4[h] - m);
            float z = ex;
            z += __shfl_xor(z, 1, 64);
            z += __shfl_xor(z, 2, 64);
            z += __shfl_xor(z, 4, 64);
            z += __shfl_xor(z, 8, 64);
            if (z == 0.f) z = 1.f;
            float a = __fdividef(ex, z);
            wg[h] = sqrtf(fmaxf(a, 0.f));
        }
        float4 o; o.x = wg[0]; o.y = wg[1]; o.z = wg[2]; o.w = wg[3];
        *(float4*)(s_wgt + lane * 4) = o;
    }
    mlp_layer(wsw + WS_WV2, s_h1 + 4608, s_h2, ct12, lane, eh * 2, eh * 2 + 2);
    __syncthreads();

    // ---- layer 3 v-path + weighting + per-edge Wout projection (MFMA K=16) ----
    {
        bf16x8 av0[5], av1[5];
#pragma unroll
        for (int ci = 0; ci < 5; ++ci) {
            int ct = w + 8 * ci;
            if (ct < 36) {
                const u16* Af = wsw + WS_WV3 + ct * 1024 + lane * 8;
                av0[ci] = *(const bf16x8*)(Af);
                av1[ci] = *(const bf16x8*)(Af + 512);
            }
        }
        // unroll 1: one et in flight — spill-avoidance (see R9 post-mortem)
#pragma unroll 1
        for (int et = 0; et < 4; ++et) {
            const u16* br = s_h2 + (et * 16 + el) * 72 + q4 * 8;
            bf16x8 b0 = *(const bf16x8*)(br);
            bf16x8 b1 = *(const bf16x8*)(br + 32);
            float4 wg4 = *(const float4*)(s_wgt + (et * 16 + el) * 4);
            f32x4 accj[4];
#pragma unroll
            for (int jt = 0; jt < 4; ++jt) accj[jt] = (f32x4){0.f, 0.f, 0.f, 0.f};
#pragma unroll
            for (int ci = 0; ci < 5; ++ci) {
                int ct = w + 8 * ci;
                if (ct < 36) {
                    f32x4 c = {0.f, 0.f, 0.f, 0.f};
                    c = MFMA(av0[ci], b0, c);
                    c = MFMA(av1[ci], b1, c);
                    int c0q = ct * 16 + 4 * q4;
                    int h = (c0q >= 432) ? 3 : (c0q >= 288) ? 2 : (c0q >= 144) ? 1 : 0;
                    float wgt = (h == 0) ? wg4.x : (h == 1) ? wg4.y : (h == 2) ? wg4.z : wg4.w;
                    float v0, v1, v2, v3;
                    if (ct < 4) {
                        u16x4 xv = *(const u16x4*)(s_x + (et * 16 + el) * 72 + c0q);
                        v0 = c[0] * b2f(xv[0]) * wgt;
                        v1 = c[1] * b2f(xv[1]) * wgt;
                        v2 = c[2] * b2f(xv[2]) * wgt;
                        v3 = c[3] * b2f(xv[3]) * wgt;
                    } else {
                        int dd = 2 * (ct - 4) + (q4 >> 1), sb = (q4 & 1) * 4;
                        float xd = b2f(s_x[(et * 16 + el) * 72 + dd]) * wgt;
                        float4 shp = *(const float4*)(s_sh + (et * 16 + el) * 8 + sb);
                        v0 = c[0] * xd * shp.x;
                        v1 = c[1] * xd * shp.y;
                        v2 = c[2] * xd * shp.z;
                        v3 = c[3] * xd * shp.w;
                    }
                    // weighted values: A-frag layout for K=16 MFMA (m=edge el, k=4q4+r)
                    bf16x4 aw;
                    aw.x = (short)f2b(v0); aw.y = (short)f2b(v1);
                    aw.z = (short)f2b(v2); aw.w = (short)f2b(v3);
#pragma unroll
                    for (int jt = 0; jt < 4; ++jt) {
                        bf16x4 bw = *(const bf16x4*)(wsw + WS_WO + (size_t)(ct * 4 + jt) * 256 + lane * 4);
                        accj[jt] = MFMA16(aw, bw, accj[jt]);
                    }
                }
            }
            // D[m=edge 4q4+r][n=j jt*16+el]: sum own 4 edges, then cross-q4 -> node sum
#pragma unroll
            for (int jt = 0; jt < 4; ++jt) {
                float s = accj[jt][0] + accj[jt][1] + accj[jt][2] + accj[jt][3];
                s += __shfl_xor(s, 16, 64);
                s += __shfl_xor(s, 32, 64);
                if (q4 == 0) s_yp[(w * 4 + et) * 64 + jt * 16 + el] = s;
            }
        }
    }
    __syncthreads();

    // ---------------- final: sum the 8 wave partials per node ----------------
    if (tid < 256) {
        int et = tid >> 6, j = tid & 63;
        float r = 0.f;
#pragma unroll
        for (int ww = 0; ww < 8; ++ww) r += s_yp[(ww * 4 + et) * 64 + j];
        out[(long)(n0 + et) * 64 + j] = r;
    }
}

extern "C" void kernel_launch(void* const* d_in, const int* in_sizes, int n_in,
                              void* d_out, int out_size, void* d_ws, size_t ws_size,
                              hipStream_t stream) {
    const float* node_feat = (const float*)d_in[0];
    const float* edge_sh   = (const float*)d_in[1];
    const float* edge_inv  = (const float*)d_in[2];
    const float* cutoff    = (const float*)d_in[3];
    const float* Wk1       = (const float*)d_in[4];
    const float* Wk2       = (const float*)d_in[5];
    const float* Wk3       = (const float*)d_in[6];
    const float* Wv1       = (const float*)d_in[7];
    const float* Wv2       = (const float*)d_in[8];
    const float* Wv3       = (const float*)d_in[9];
    const float* Wlogit    = (const float*)d_in[10];
    const float* Wout      = (const float*)d_in[11];
    const int*   edge_src  = (const int*)d_in[12];
    float* out = (float*)d_out;
    u16* wsw = (u16*)d_ws;

    prep<<<(WS_TOTAL + 255) / 256, 256, 0, stream>>>(
        Wk1, Wk2, Wk3, Wv1, Wv2, Wv3, Wout, wsw);
    fused<<<2048, 512, 0, stream>>>(
        node_feat, edge_sh, edge_inv, cutoff, Wlogit, edge_src, wsw, out);
}

// Round 12
// 169.456 us; speedup vs baseline: 1.2796x; 1.0028x over previous
//
#include <hip/hip_runtime.h>
#include <math.h>

typedef unsigned short u16;
typedef short bf16x8 __attribute__((ext_vector_type(8)));
typedef short bf16x4 __attribute__((ext_vector_type(4)));
typedef unsigned short u16x4 __attribute__((ext_vector_type(4)));
typedef float f32x4 __attribute__((ext_vector_type(4)));

#define MFMA(a,b,c)   __builtin_amdgcn_mfma_f32_16x16x32_bf16((a),(b),(c),0,0,0)
#define MFMA16(a,b,c) __builtin_amdgcn_mfma_f32_16x16x16bf16_1k((a),(b),(c),0,0,0)

// ws layout (u16 elements): pre-swizzled bf16 MFMA A/B fragments
#define WS_WK1 0
#define WS_WV1 8192
#define WS_WK2 16384
#define WS_WV2 24576
#define WS_WK3 32768
#define WS_WV3 69632
#define WS_WO  106496      // 144 frags (ct 36 x jt 4) x 256 u16, B-layout K=16
#define WS_TOTAL 143360

// LDS byte offsets (64 edges / 4 nodes per block) — total 52480 B
#define OFF_H1   0        // [2][64][72] u16 = 18432  (overlay: s_yp [8][4][64] f32)
#define OFF_H2   18432    // [64][72] u16 = 9216 (single buffer, k then v)
#define OFF_INV  27648    // [64][72] u16 = 9216      (overlay: s_lp [8][64][4] f32)
#define OFF_X    36864    // [64][72] u16 = 9216
#define OFF_SH   46080    // [64][8] f32 = 2048
#define OFF_Q    48128    // [4][64] f32 = 1024
#define OFF_CUT  49152    // [64] f32 = 256
#define OFF_WL   49408    // [128][4] f32 = 2048
#define OFF_WGT  51456    // [64][4] f32 = 1024
#define SMEM_SZ  52480

__device__ __forceinline__ u16 f2b(float f) {
    unsigned int u; __builtin_memcpy(&u, &f, 4);
    u += 0x7FFFu + ((u >> 16) & 1u);          // round-to-nearest-even
    return (u16)(u >> 16);
}
__device__ __forceinline__ float b2f(u16 v) {
    unsigned int u = ((unsigned int)v) << 16;
    float f; __builtin_memcpy(&f, &u, 4);
    return f;
}
__device__ __forceinline__ u16x4 pack4(float4 v) {
    u16x4 o; o.x = f2b(v.x); o.y = f2b(v.y); o.z = f2b(v.z); o.w = f2b(v.w);
    return o;
}
// gelu(tanh form) rearranged: 0.5x(1+tanh(u)) == x * sigmoid(2u) == x / (1 + e^{-2u})
__device__ __forceinline__ float gelu(float x) {
    const float c1 = 0.044715f;
    const float K  = -2.0f * 0.7978845608028654f * 1.4426950408889634f;
    float t  = x * x;
    float t2 = fmaf(c1, t, 1.0f);
    float p  = (K * x) * t2;
    float e  = __builtin_amdgcn_exp2f(p);
    float r  = __builtin_amdgcn_rcpf(1.0f + e);
    return x * r;
}

// ---------------- weight pre-swizzle: fp32 [K x N] -> bf16 MFMA frags ----------------
__global__ void prep(const float* __restrict__ Wk1, const float* __restrict__ Wk2,
                     const float* __restrict__ Wk3, const float* __restrict__ Wv1,
                     const float* __restrict__ Wv2, const float* __restrict__ Wv3,
                     const float* __restrict__ Wout, u16* __restrict__ wsw) {
    int i = blockIdx.x * 256 + threadIdx.x;
    if (i >= WS_TOTAL) return;
    if (i >= WS_WO) {
        // Wout as B-operand frags for v_mfma_f32_16x16x16_bf16:
        // frag f = ct*4+jt; lane l holds B[n=j][k=c]: n=jt*16+(l&15), k=ct*16+(l>>4)*4+j4
        int pos = i - WS_WO;
        int f = pos >> 8, idx = pos & 255;
        int l = idx >> 2, j4 = idx & 3;
        int ct = f >> 2, jt = f & 3;
        int c = ct * 16 + ((l >> 4) << 2) + j4;
        int j = jt * 16 + (l & 15);
        wsw[i] = f2b(Wout[c * 64 + j]);
        return;
    }
    const float* W; int Kd, Nd, pos;
    if      (i < WS_WV1) { W = Wk1;  Kd = 64;  Nd = 64;  pos = i; }
    else if (i < WS_WK2) { W = Wv1;  Kd = 64;  Nd = 64;  pos = i - WS_WV1; }
    else if (i < WS_WV2) { W = Wk2;  Kd = 64;  Nd = 64;  pos = i - WS_WK2; }
    else if (i < WS_WK3) { W = Wv2;  Kd = 64;  Nd = 64;  pos = i - WS_WV2; }
    else if (i < WS_WV3) { W = Wk3;  Kd = 64;  Nd = 576; pos = i - WS_WK3; }
    else                 { W = Wv3;  Kd = 64;  Nd = 576; pos = i - WS_WV3; }
    int f = pos >> 9, rr = pos & 511, l = rr >> 3, j = rr & 7;
    int ktN = Kd >> 5;
    int mt = f / ktN, kt = f - mt * ktN;
    int m = mt * 16 + (l & 15);
    int k = kt * 32 + ((l >> 4) << 3) + j;
    wsw[i] = f2b(W[k * Nd + m]);
}

// one (ct, et-range) task: D[16ch x 16e] tiles = W^T*act, gelu, store [e][ch] bf16
__device__ __forceinline__ void mlp_layer(const u16* __restrict__ Wf,
                                          const u16* __restrict__ sin,
                                          u16* __restrict__ sout,
                                          int ct, int lane, int et0, int et1) {
    const int q = lane >> 4, el = lane & 15;
    bf16x8 a0 = *(const bf16x8*)(Wf + (ct * 2 + 0) * 512 + lane * 8);
    bf16x8 a1 = *(const bf16x8*)(Wf + (ct * 2 + 1) * 512 + lane * 8);
    for (int et = et0; et < et1; ++et) {
        const u16* br = sin + (et * 16 + el) * 72 + q * 8;
        bf16x8 b0 = *(const bf16x8*)(br);
        bf16x8 b1 = *(const bf16x8*)(br + 32);
        f32x4 c = {0.f, 0.f, 0.f, 0.f};
        c = MFMA(a0, b0, c);
        c = MFMA(a1, b1, c);
        u16x4 o;
        o.x = f2b(gelu(c[0])); o.y = f2b(gelu(c[1]));
        o.z = f2b(gelu(c[2])); o.w = f2b(gelu(c[3]));
        *(u16x4*)(sout + (et * 16 + el) * 72 + ct * 16 + q * 4) = o;
    }
}

// waves_per_eu(4,4): pin allocator to exactly 4 waves/SIMD -> 128-VGPR budget
// (the default targets 8 waves/SIMD = 64 VGPR and spills instead of exceeding it)
__global__ __attribute__((amdgpu_flat_work_group_size(512, 512)))
__attribute__((amdgpu_waves_per_eu(4, 4))) void fused(
    const float* __restrict__ node_feat, const float* __restrict__ edge_sh,
    const float* __restrict__ edge_inv, const float* __restrict__ cutoff,
    const float* __restrict__ Wlogit, const int* __restrict__ edge_src,
    const u16* __restrict__ wsw, float* __restrict__ out)
{
    __shared__ __align__(16) unsigned char smem[SMEM_SZ];
    u16*   s_h1  = (u16*)(smem + OFF_H1);     // [2][64][72]
    u16*   s_h2  = (u16*)(smem + OFF_H2);     // [64][72] (k then v)
    u16*   s_inv = (u16*)(smem + OFF_INV);    // [64][72]
    u16*   s_x   = (u16*)(smem + OFF_X);      // [64][72]
    float* s_sh  = (float*)(smem + OFF_SH);   // [64][8]
    float* s_q   = (float*)(smem + OFF_Q);    // [4][64]
    float* s_cut = (float*)(smem + OFF_CUT);  // [64]
    float* s_wl  = (float*)(smem + OFF_WL);   // [128][4]
    float* s_wgt = (float*)(smem + OFF_WGT);  // [64][4]
    float* s_lp  = (float*)(smem + OFF_INV);  // overlay (inv dead after L1): [8][64][4]
    float* s_yp  = (float*)(smem + OFF_H1);   // overlay (h1k dead after L2k): [8][4][64]

    const int tid = threadIdx.x;
    const int lane = tid & 63;
    const int w = tid >> 6;
    const int q4 = lane >> 4;     // quad
    const int el = lane & 15;
    const int blk = blockIdx.x;
    const int n0 = blk * 4;
    const long e0 = (long)blk * 64;

    // ---------------- stage ----------------
    if (tid < 64)  s_cut[tid] = cutoff[e0 + tid];
    if (tid < 256) s_q[tid] = node_feat[(long)(n0 + (tid >> 6)) * 64 + (tid & 63)];
    s_wl[tid] = Wlogit[tid];
    s_sh[tid] = edge_sh[e0 * 8 + tid];
    { int row = tid >> 3, part = tid & 7;
      const float4* src = (const float4*)(edge_inv + (e0 + row) * 64) + part * 2;
      u16x4* dst = (u16x4*)(s_inv + row * 72 + part * 8);
      dst[0] = pack4(src[0]); dst[1] = pack4(src[1]);
      int sr = edge_src[e0 + row];
      const float4* sx = (const float4*)(node_feat + (long)sr * 64) + part * 2;
      u16x4* dx = (u16x4*)(s_x + row * 72 + part * 8);
      dx[0] = pack4(sx[0]); dx[1] = pack4(sx[1]);
    }
    __syncthreads();

    // ---------------- layer 1 (k & v in parallel across waves) ----------------
    const int mat = w >> 2, ct12 = w & 3;
    mlp_layer(wsw + (mat ? WS_WV1 : WS_WK1), s_inv, s_h1 + mat * 4608, ct12, lane, 0, 4);
    __syncthreads();

    // ---------------- layer 2 (k only, all 8 waves: 4 ct x 2 et-halves) ----------------
    const int eh = w >> 2;
    mlp_layer(wsw + WS_WK2, s_h1, s_h2, ct12, lane, eh * 2, eh * 2 + 2);
    __syncthreads();

    // ---------------- layer 3 k-path + logits ----------------
    {
        bf16x8 ak0[5], ak1[5];
#pragma unroll
        for (int ci = 0; ci < 5; ++ci) {
            int ct = w + 8 * ci;
            if (ct < 36) {
                const u16* Af = wsw + WS_WK3 + ct * 1024 + lane * 8;
                ak0[ci] = *(const bf16x8*)(Af);
                ak1[ci] = *(const bf16x8*)(Af + 512);
            }
        }
        // unroll 2: two et chains in flight (ILP) while staying under 128 VGPR
#pragma unroll 2
        for (int et = 0; et < 4; ++et) {
            const u16* br = s_h2 + (et * 16 + el) * 72 + q4 * 8;
            bf16x8 b0 = *(const bf16x8*)(br);
            bf16x8 b1 = *(const bf16x8*)(br + 32);
            float L0 = 0.f, L1 = 0.f, L2 = 0.f, L3 = 0.f;
#pragma unroll
            for (int ci = 0; ci < 5; ++ci) {
                int ct = w + 8 * ci;
                if (ct < 36) {
                    f32x4 c = {0.f, 0.f, 0.f, 0.f};
                    c = MFMA(ak0[ci], b0, c);
                    c = MFMA(ak1[ci], b1, c);
                    if (ct < 4) {
                        const float* qp = s_q + et * 64 + ct * 16 + 4 * q4;
                        u16x4 xv = *(const u16x4*)(s_x + (et * 16 + el) * 72 + ct * 16 + 4 * q4);
#pragma unroll
                        for (int r = 0; r < 4; ++r) {
                            const float* wlp = s_wl + (ct * 16 + 4 * q4 + r) * 4;
                            float wk = c[r] * qp[r] * b2f(xv[r]);
                            L0 += wk * wlp[0]; L1 += wk * wlp[1];
                            L2 += wk * wlp[2]; L3 += wk * wlp[3];
                        }
                    } else {
                        int dd = 2 * (ct - 4) + (q4 >> 1), sb = (q4 & 1) * 4;
                        float qd = s_q[et * 64 + dd];
                        float xd = b2f(s_x[(et * 16 + el) * 72 + dd]);
                        float4 sp = *(const float4*)(s_sh + (et * 16 + el) * 8 + sb);
                        float ss = c[0]*sp.x*sp.x + c[1]*sp.y*sp.y + c[2]*sp.z*sp.z + c[3]*sp.w*sp.w;
                        float wk = ss * qd * xd;
                        const float* wlp = s_wl + (64 + dd) * 4;
                        L0 += wk * wlp[0]; L1 += wk * wlp[1];
                        L2 += wk * wlp[2]; L3 += wk * wlp[3];
                    }
                }
            }
            L0 += __shfl_xor(L0, 16, 64); L0 += __shfl_xor(L0, 32, 64);
            L1 += __shfl_xor(L1, 16, 64); L1 += __shfl_xor(L1, 32, 64);
            L2 += __shfl_xor(L2, 16, 64); L2 += __shfl_xor(L2, 32, 64);
            L3 += __shfl_xor(L3, 16, 64); L3 += __shfl_xor(L3, 32, 64);
            if (lane < 16) {
                float* p = s_lp + w * 256 + (et * 16 + lane) * 4;
                p[0] = L0; p[1] = L1; p[2] = L2; p[3] = L3;
            }
        }
    }
    __syncthreads();

    // -------- softmax (wave 0) concurrent with layer 2 (v, all waves) --------
    if (w == 0) {
        float l4[4] = {0.f, 0.f, 0.f, 0.f};
#pragma unroll
        for (int ww = 0; ww < 8; ++ww) {
            float4 p = *(const float4*)(s_lp + ww * 256 + lane * 4);
            l4[0] += p.x; l4[1] += p.y; l4[2] += p.z; l4[3] += p.w;
        }
        float cut = s_cut[lane];
        float wg[4];
#pragma unroll
        for (int h = 0; h < 4; ++h) {
            float m = l4[h];
            m = fmaxf(m, __shfl_xor(m, 1, 64));
            m = fmaxf(m, __shfl_xor(m, 2, 64));
            m = fmaxf(m, __shfl_xor(m, 4, 64));
            m = fmaxf(m, __shfl_xor(m, 8, 64));
            float ex = cut * __expf(l4[h] - m);
            float z = ex;
            z += __shfl_xor(z, 1, 64);
            z += __shfl_xor(z, 2, 64);
            z += __shfl_xor(z, 4, 64);
            z += __shfl_xor(z, 8, 64);
            if (z == 0.f) z = 1.f;
            float a = __fdividef(ex, z);
            wg[h] = sqrtf(fmaxf(a, 0.f));
        }
        float4 o; o.x = wg[0]; o.y = wg[1]; o.z = wg[2]; o.w = wg[3];
        *(float4*)(s_wgt + lane * 4) = o;
    }
    mlp_layer(wsw + WS_WV2, s_h1 + 4608, s_h2, ct12, lane, eh * 2, eh * 2 + 2);
    __syncthreads();

    // ---- layer 3 v-path + weighting + per-edge Wout projection (MFMA K=16) ----
    {
        bf16x8 av0[5], av1[5];
#pragma unroll
        for (int ci = 0; ci < 5; ++ci) {
            int ct = w + 8 * ci;
            if (ct < 36) {
                const u16* Af = wsw + WS_WV3 + ct * 1024 + lane * 8;
                av0[ci] = *(const bf16x8*)(Af);
                av1[ci] = *(const bf16x8*)(Af + 512);
            }
        }
        // unroll 2: two et chains in flight — ILP within the 128-VGPR budget
#pragma unroll 2
        for (int et = 0; et < 4; ++et) {
            const u16* br = s_h2 + (et * 16 + el) * 72 + q4 * 8;
            bf16x8 b0 = *(const bf16x8*)(br);
            bf16x8 b1 = *(const bf16x8*)(br + 32);
            float4 wg4 = *(const float4*)(s_wgt + (et * 16 + el) * 4);
            f32x4 accj[4];
#pragma unroll
            for (int jt = 0; jt < 4; ++jt) accj[jt] = (f32x4){0.f, 0.f, 0.f, 0.f};
#pragma unroll
            for (int ci = 0; ci < 5; ++ci) {
                int ct = w + 8 * ci;
                if (ct < 36) {
                    f32x4 c = {0.f, 0.f, 0.f, 0.f};
                    c = MFMA(av0[ci], b0, c);
                    c = MFMA(av1[ci], b1, c);
                    int c0q = ct * 16 + 4 * q4;
                    int h = (c0q >= 432) ? 3 : (c0q >= 288) ? 2 : (c0q >= 144) ? 1 : 0;
                    float wgt = (h == 0) ? wg4.x : (h == 1) ? wg4.y : (h == 2) ? wg4.z : wg4.w;
                    float v0, v1, v2, v3;
                    if (ct < 4) {
                        u16x4 xv = *(const u16x4*)(s_x + (et * 16 + el) * 72 + c0q);
                        v0 = c[0] * b2f(xv[0]) * wgt;
                        v1 = c[1] * b2f(xv[1]) * wgt;
                        v2 = c[2] * b2f(xv[2]) * wgt;
                        v3 = c[3] * b2f(xv[3]) * wgt;
                    } else {
                        int dd = 2 * (ct - 4) + (q4 >> 1), sb = (q4 & 1) * 4;
                        float xd = b2f(s_x[(et * 16 + el) * 72 + dd]) * wgt;
                        float4 shp = *(const float4*)(s_sh + (et * 16 + el) * 8 + sb);
                        v0 = c[0] * xd * shp.x;
                        v1 = c[1] * xd * shp.y;
                        v2 = c[2] * xd * shp.z;
                        v3 = c[3] * xd * shp.w;
                    }
                    // weighted values: A-frag layout for K=16 MFMA (m=edge el, k=4q4+r)
                    bf16x4 aw;
                    aw.x = (short)f2b(v0); aw.y = (short)f2b(v1);
                    aw.z = (short)f2b(v2); aw.w = (short)f2b(v3);
#pragma unroll
                    for (int jt = 0; jt < 4; ++jt) {
                        bf16x4 bw = *(const bf16x4*)(wsw + WS_WO + (size_t)(ct * 4 + jt) * 256 + lane * 4);
                        accj[jt] = MFMA16(aw, bw, accj[jt]);
                    }
                }
            }
            // D[m=edge 4q4+r][n=j jt*16+el]: sum own 4 edges, then cross-q4 -> node sum
#pragma unroll
            for (int jt = 0; jt < 4; ++jt) {
                float s = accj[jt][0] + accj[jt][1] + accj[jt][2] + accj[jt][3];
                s += __shfl_xor(s, 16, 64);
                s += __shfl_xor(s, 32, 64);
                if (q4 == 0) s_yp[(w * 4 + et) * 64 + jt * 16 + el] = s;
            }
        }
    }
    __syncthreads();

    // ---------------- final: sum the 8 wave partials per node ----------------
    if (tid < 256) {
        int et = tid >> 6, j = tid & 63;
        float r = 0.f;
#pragma unroll
        for (int ww = 0; ww < 8; ++ww) r += s_yp[(ww * 4 + et) * 64 + j];
        out[(long)(n0 + et) * 64 + j] = r;
    }
}

extern "C" void kernel_launch(void* const* d_in, const int* in_sizes, int n_in,
                              void* d_out, int out_size, void* d_ws, size_t ws_size,
                              hipStream_t stream) {
    const float* node_feat = (const float*)d_in[0];
    const float* edge_sh   = (const float*)d_in[1];
    const float* edge_inv  = (const float*)d_in[2];
    const float* cutoff    = (const float*)d_in[3];
    const float* Wk1       = (const float*)d_in[4];
    const float* Wk2       = (const float*)d_in[5];
    const float* Wk3       = (const float*)d_in[6];
    const float* Wv1       = (const float*)d_in[7];
    const float* Wv2       = (const float*)d_in[8];
    const float* Wv3       = (const float*)d_in[9];
    const float* Wlogit    = (const float*)d_in[10];
    const float* Wout      = (const float*)d_in[11];
    const int*   edge_src  = (const int*)d_in[12];
    float* out = (float*)d_out;
    u16* wsw = (u16*)d_ws;

    prep<<<(WS_TOTAL + 255) / 256, 256, 0, stream>>>(
        Wk1, Wk2, Wk3, Wv1, Wv2, Wv3, Wout, wsw);
    fused<<<2048, 512, 0, stream>>>(
        node_feat, edge_sh, edge_inv, cutoff, Wlogit, edge_src, wsw, out);
}

// Round 13
// 168.212 us; speedup vs baseline: 1.2890x; 1.0074x over previous
//
#include <hip/hip_runtime.h>
#include <math.h>

typedef unsigned short u16;
typedef short bf16x8 __attribute__((ext_vector_type(8)));
typedef short bf16x4 __attribute__((ext_vector_type(4)));
typedef unsigned short u16x4 __attribute__((ext_vector_type(4)));
typedef float f32x4 __attribute__((ext_vector_type(4)));

#define MFMA(a,b,c)   __builtin_amdgcn_mfma_f32_16x16x32_bf16((a),(b),(c),0,0,0)
#define MFMA16(a,b,c) __builtin_amdgcn_mfma_f32_16x16x16bf16_1k((a),(b),(c),0,0,0)

// ws layout (u16 elements): pre-swizzled bf16 MFMA A/B fragments
#define WS_WK1 0
#define WS_WV1 8192
#define WS_WK2 16384
#define WS_WV2 24576
#define WS_WK3 32768
#define WS_WV3 69632
#define WS_WO  106496      // 144 frags (ct 36 x jt 4) x 256 u16, B-layout K=16
#define WS_TOTAL 143360

// LDS byte offsets (64 edges / 4 nodes per block) — total 52480 B
#define OFF_H1   0        // [2][64][72] u16 = 18432  (overlay: s_yp [8][4][64] f32)
#define OFF_H2   18432    // [64][72] u16 = 9216 (single buffer, k then v)
#define OFF_INV  27648    // [64][72] u16 = 9216      (overlay: s_lp [8][64][4] f32)
#define OFF_X    36864    // [64][72] u16 = 9216
#define OFF_SH   46080    // [64][8] f32 = 2048
#define OFF_Q    48128    // [4][64] f32 = 1024
#define OFF_CUT  49152    // [64] f32 = 256
#define OFF_WL   49408    // [128][4] f32 = 2048
#define OFF_WGT  51456    // [64][4] f32 = 1024
#define SMEM_SZ  52480

__device__ __forceinline__ u16 f2b(float f) {
    unsigned int u; __builtin_memcpy(&u, &f, 4);
    u += 0x7FFFu + ((u >> 16) & 1u);          // round-to-nearest-even
    return (u16)(u >> 16);
}
__device__ __forceinline__ float b2f(u16 v) {
    unsigned int u = ((unsigned int)v) << 16;
    float f; __builtin_memcpy(&f, &u, 4);
    return f;
}
__device__ __forceinline__ u16x4 pack4(float4 v) {
    u16x4 o; o.x = f2b(v.x); o.y = f2b(v.y); o.z = f2b(v.z); o.w = f2b(v.w);
    return o;
}
// gelu(tanh form) rearranged: 0.5x(1+tanh(u)) == x * sigmoid(2u) == x / (1 + e^{-2u})
__device__ __forceinline__ float gelu(float x) {
    const float c1 = 0.044715f;
    const float K  = -2.0f * 0.7978845608028654f * 1.4426950408889634f;
    float t  = x * x;
    float t2 = fmaf(c1, t, 1.0f);
    float p  = (K * x) * t2;
    float e  = __builtin_amdgcn_exp2f(p);
    float r  = __builtin_amdgcn_rcpf(1.0f + e);
    return x * r;
}

// ---------------- weight pre-swizzle: fp32 [K x N] -> bf16 MFMA frags ----------------
__global__ void prep(const float* __restrict__ Wk1, const float* __restrict__ Wk2,
                     const float* __restrict__ Wk3, const float* __restrict__ Wv1,
                     const float* __restrict__ Wv2, const float* __restrict__ Wv3,
                     const float* __restrict__ Wout, u16* __restrict__ wsw) {
    int i = blockIdx.x * 256 + threadIdx.x;
    if (i >= WS_TOTAL) return;
    if (i >= WS_WO) {
        // Wout as B-operand frags for v_mfma_f32_16x16x16_bf16:
        // frag f = ct*4+jt; lane l holds B[n=j][k=c]: n=jt*16+(l&15), k=ct*16+(l>>4)*4+j4
        int pos = i - WS_WO;
        int f = pos >> 8, idx = pos & 255;
        int l = idx >> 2, j4 = idx & 3;
        int ct = f >> 2, jt = f & 3;
        int c = ct * 16 + ((l >> 4) << 2) + j4;
        int j = jt * 16 + (l & 15);
        wsw[i] = f2b(Wout[c * 64 + j]);
        return;
    }
    const float* W; int Kd, Nd, pos;
    if      (i < WS_WV1) { W = Wk1;  Kd = 64;  Nd = 64;  pos = i; }
    else if (i < WS_WK2) { W = Wv1;  Kd = 64;  Nd = 64;  pos = i - WS_WV1; }
    else if (i < WS_WV2) { W = Wk2;  Kd = 64;  Nd = 64;  pos = i - WS_WK2; }
    else if (i < WS_WK3) { W = Wv2;  Kd = 64;  Nd = 64;  pos = i - WS_WV2; }
    else if (i < WS_WV3) { W = Wk3;  Kd = 64;  Nd = 576; pos = i - WS_WK3; }
    else                 { W = Wv3;  Kd = 64;  Nd = 576; pos = i - WS_WV3; }
    int f = pos >> 9, rr = pos & 511, l = rr >> 3, j = rr & 7;
    int ktN = Kd >> 5;
    int mt = f / ktN, kt = f - mt * ktN;
    int m = mt * 16 + (l & 15);
    int k = kt * 32 + ((l >> 4) << 3) + j;
    wsw[i] = f2b(W[k * Nd + m]);
}

// one (ct, et-range) task: D[16ch x 16e] tiles = W^T*act, gelu, store [e][ch] bf16
__device__ __forceinline__ void mlp_layer(const u16* __restrict__ Wf,
                                          const u16* __restrict__ sin,
                                          u16* __restrict__ sout,
                                          int ct, int lane, int et0, int et1) {
    const int q = lane >> 4, el = lane & 15;
    bf16x8 a0 = *(const bf16x8*)(Wf + (ct * 2 + 0) * 512 + lane * 8);
    bf16x8 a1 = *(const bf16x8*)(Wf + (ct * 2 + 1) * 512 + lane * 8);
    for (int et = et0; et < et1; ++et) {
        const u16* br = sin + (et * 16 + el) * 72 + q * 8;
        bf16x8 b0 = *(const bf16x8*)(br);
        bf16x8 b1 = *(const bf16x8*)(br + 32);
        f32x4 c = {0.f, 0.f, 0.f, 0.f};
        c = MFMA(a0, b0, c);
        c = MFMA(a1, b1, c);
        u16x4 o;
        o.x = f2b(gelu(c[0])); o.y = f2b(gelu(c[1]));
        o.z = f2b(gelu(c[2])); o.w = f2b(gelu(c[3]));
        *(u16x4*)(sout + (et * 16 + el) * 72 + ct * 16 + q * 4) = o;
    }
}

// waves_per_eu(4,4): pin allocator to exactly 4 waves/SIMD -> 128-VGPR budget
// (the default targets 8 waves/SIMD = 64 VGPR and spills instead of exceeding it)
__global__ __attribute__((amdgpu_flat_work_group_size(512, 512)))
__attribute__((amdgpu_waves_per_eu(4, 4))) void fused(
    const float* __restrict__ node_feat, const float* __restrict__ edge_sh,
    const float* __restrict__ edge_inv, const float* __restrict__ cutoff,
    const float* __restrict__ Wlogit, const int* __restrict__ edge_src,
    const u16* __restrict__ wsw, float* __restrict__ out)
{
    __shared__ __align__(16) unsigned char smem[SMEM_SZ];
    u16*   s_h1  = (u16*)(smem + OFF_H1);     // [2][64][72]
    u16*   s_h2  = (u16*)(smem + OFF_H2);     // [64][72] (k then v)
    u16*   s_inv = (u16*)(smem + OFF_INV);    // [64][72]
    u16*   s_x   = (u16*)(smem + OFF_X);      // [64][72]
    float* s_sh  = (float*)(smem + OFF_SH);   // [64][8]
    float* s_q   = (float*)(smem + OFF_Q);    // [4][64]
    float* s_cut = (float*)(smem + OFF_CUT);  // [64]
    float* s_wl  = (float*)(smem + OFF_WL);   // [128][4]
    float* s_wgt = (float*)(smem + OFF_WGT);  // [64][4]
    float* s_lp  = (float*)(smem + OFF_INV);  // overlay (inv dead after L1): [8][64][4]
    float* s_yp  = (float*)(smem + OFF_H1);   // overlay (h1k dead after L2k): [8][4][64]

    const int tid = threadIdx.x;
    const int lane = tid & 63;
    const int w = tid >> 6;
    const int q4 = lane >> 4;     // quad
    const int el = lane & 15;
    const int blk = blockIdx.x;
    const int n0 = blk * 4;
    const long e0 = (long)blk * 64;

    // ---------------- stage ----------------
    if (tid < 64)  s_cut[tid] = cutoff[e0 + tid];
    if (tid < 256) s_q[tid] = node_feat[(long)(n0 + (tid >> 6)) * 64 + (tid & 63)];
    s_wl[tid] = Wlogit[tid];
    s_sh[tid] = edge_sh[e0 * 8 + tid];
    { int row = tid >> 3, part = tid & 7;
      const float4* src = (const float4*)(edge_inv + (e0 + row) * 64) + part * 2;
      u16x4* dst = (u16x4*)(s_inv + row * 72 + part * 8);
      dst[0] = pack4(src[0]); dst[1] = pack4(src[1]);
      int sr = edge_src[e0 + row];
      const float4* sx = (const float4*)(node_feat + (long)sr * 64) + part * 2;
      u16x4* dx = (u16x4*)(s_x + row * 72 + part * 8);
      dx[0] = pack4(sx[0]); dx[1] = pack4(sx[1]);
    }
    __syncthreads();

    // ---------------- layer 1 (k & v in parallel across waves) ----------------
    const int mat = w >> 2, ct12 = w & 3;
    mlp_layer(wsw + (mat ? WS_WV1 : WS_WK1), s_inv, s_h1 + mat * 4608, ct12, lane, 0, 4);
    __syncthreads();

    // ---------------- layer 2 (k only, all 8 waves: 4 ct x 2 et-halves) ----------------
    const int eh = w >> 2;
    mlp_layer(wsw + WS_WK2, s_h1, s_h2, ct12, lane, eh * 2, eh * 2 + 2);
    __syncthreads();

    // ---------------- layer 3 k-path + logits ----------------
    {
        bf16x8 ak0[5], ak1[5];
#pragma unroll
        for (int ci = 0; ci < 5; ++ci) {
            int ct = w + 8 * ci;
            if (ct < 36) {
                const u16* Af = wsw + WS_WK3 + ct * 1024 + lane * 8;
                ak0[ci] = *(const bf16x8*)(Af);
                ak1[ci] = *(const bf16x8*)(Af + 512);
            }
        }
        // full unroll: 4 independent chains; live set ~105 VGPR < 128 budget
#pragma unroll
        for (int et = 0; et < 4; ++et) {
            const u16* br = s_h2 + (et * 16 + el) * 72 + q4 * 8;
            bf16x8 b0 = *(const bf16x8*)(br);
            bf16x8 b1 = *(const bf16x8*)(br + 32);
            float L0 = 0.f, L1 = 0.f, L2 = 0.f, L3 = 0.f;
#pragma unroll
            for (int ci = 0; ci < 5; ++ci) {
                int ct = w + 8 * ci;
                if (ct < 36) {
                    f32x4 c = {0.f, 0.f, 0.f, 0.f};
                    c = MFMA(ak0[ci], b0, c);
                    c = MFMA(ak1[ci], b1, c);
                    if (ct < 4) {
                        const float* qp = s_q + et * 64 + ct * 16 + 4 * q4;
                        u16x4 xv = *(const u16x4*)(s_x + (et * 16 + el) * 72 + ct * 16 + 4 * q4);
#pragma unroll
                        for (int r = 0; r < 4; ++r) {
                            const float* wlp = s_wl + (ct * 16 + 4 * q4 + r) * 4;
                            float wk = c[r] * qp[r] * b2f(xv[r]);
                            L0 += wk * wlp[0]; L1 += wk * wlp[1];
                            L2 += wk * wlp[2]; L3 += wk * wlp[3];
                        }
                    } else {
                        int dd = 2 * (ct - 4) + (q4 >> 1), sb = (q4 & 1) * 4;
                        float qd = s_q[et * 64 + dd];
                        float xd = b2f(s_x[(et * 16 + el) * 72 + dd]);
                        float4 sp = *(const float4*)(s_sh + (et * 16 + el) * 8 + sb);
                        float ss = c[0]*sp.x*sp.x + c[1]*sp.y*sp.y + c[2]*sp.z*sp.z + c[3]*sp.w*sp.w;
                        float wk = ss * qd * xd;
                        const float* wlp = s_wl + (64 + dd) * 4;
                        L0 += wk * wlp[0]; L1 += wk * wlp[1];
                        L2 += wk * wlp[2]; L3 += wk * wlp[3];
                    }
                }
            }
            L0 += __shfl_xor(L0, 16, 64); L0 += __shfl_xor(L0, 32, 64);
            L1 += __shfl_xor(L1, 16, 64); L1 += __shfl_xor(L1, 32, 64);
            L2 += __shfl_xor(L2, 16, 64); L2 += __shfl_xor(L2, 32, 64);
            L3 += __shfl_xor(L3, 16, 64); L3 += __shfl_xor(L3, 32, 64);
            if (lane < 16) {
                float* p = s_lp + w * 256 + (et * 16 + lane) * 4;
                p[0] = L0; p[1] = L1; p[2] = L2; p[3] = L3;
            }
        }
    }
    __syncthreads();

    // -------- softmax (wave 0) concurrent with layer 2 (v, all waves) --------
    if (w == 0) {
        float l4[4] = {0.f, 0.f, 0.f, 0.f};
#pragma unroll
        for (int ww = 0; ww < 8; ++ww) {
            float4 p = *(const float4*)(s_lp + ww * 256 + lane * 4);
            l4[0] += p.x; l4[1] += p.y; l4[2] += p.z; l4[3] += p.w;
        }
        float cut = s_cut[lane];
        float wg[4];
#pragma unroll
        for (int h = 0; h < 4; ++h) {
            float m = l4[h];
            m = fmaxf(m, __shfl_xor(m, 1, 64));
            m = fmaxf(m, __shfl_xor(m, 2, 64));
            m = fmaxf(m, __shfl_xor(m, 4, 64));
            m = fmaxf(m, __shfl_xor(m, 8, 64));
            float ex = cut * __expf(l4[h] - m);
            float z = ex;
            z += __shfl_xor(z, 1, 64);
            z += __shfl_xor(z, 2, 64);
            z += __shfl_xor(z, 4, 64);
            z += __shfl_xor(z, 8, 64);
            if (z == 0.f) z = 1.f;
            float a = __fdividef(ex, z);
            wg[h] = sqrtf(fmaxf(a, 0.f));
        }
        float4 o; o.x = wg[0]; o.y = wg[1]; o.z = wg[2]; o.w = wg[3];
        *(float4*)(s_wgt + lane * 4) = o;
    }
    mlp_layer(wsw + WS_WV2, s_h1 + 4608, s_h2, ct12, lane, eh * 2, eh * 2 + 2);
    __syncthreads();

    // ---- layer 3 v-path + weighting + per-edge Wout projection (MFMA K=16) ----
    {
        bf16x8 av0[5], av1[5];
#pragma unroll
        for (int ci = 0; ci < 5; ++ci) {
            int ct = w + 8 * ci;
            if (ct < 36) {
                const u16* Af = wsw + WS_WV3 + ct * 1024 + lane * 8;
                av0[ci] = *(const bf16x8*)(Af);
                av1[ci] = *(const bf16x8*)(Af + 512);
            }
        }
        // unroll 2: full unroll here would need ~136 VGPR (av 40 + 4x16 accj + b)
        // and spill — keep two chains in flight (R12-verified spill-free)
#pragma unroll 2
        for (int et = 0; et < 4; ++et) {
            const u16* br = s_h2 + (et * 16 + el) * 72 + q4 * 8;
            bf16x8 b0 = *(const bf16x8*)(br);
            bf16x8 b1 = *(const bf16x8*)(br + 32);
            float4 wg4 = *(const float4*)(s_wgt + (et * 16 + el) * 4);
            f32x4 accj[4];
#pragma unroll
            for (int jt = 0; jt < 4; ++jt) accj[jt] = (f32x4){0.f, 0.f, 0.f, 0.f};
#pragma unroll
            for (int ci = 0; ci < 5; ++ci) {
                int ct = w + 8 * ci;
                if (ct < 36) {
                    f32x4 c = {0.f, 0.f, 0.f, 0.f};
                    c = MFMA(av0[ci], b0, c);
                    c = MFMA(av1[ci], b1, c);
                    int c0q = ct * 16 + 4 * q4;
                    int h = (c0q >= 432) ? 3 : (c0q >= 288) ? 2 : (c0q >= 144) ? 1 : 0;
                    float wgt = (h == 0) ? wg4.x : (h == 1) ? wg4.y : (h == 2) ? wg4.z : wg4.w;
                    float v0, v1, v2, v3;
                    if (ct < 4) {
                        u16x4 xv = *(const u16x4*)(s_x + (et * 16 + el) * 72 + c0q);
                        v0 = c[0] * b2f(xv[0]) * wgt;
                        v1 = c[1] * b2f(xv[1]) * wgt;
                        v2 = c[2] * b2f(xv[2]) * wgt;
                        v3 = c[3] * b2f(xv[3]) * wgt;
                    } else {
                        int dd = 2 * (ct - 4) + (q4 >> 1), sb = (q4 & 1) * 4;
                        float xd = b2f(s_x[(et * 16 + el) * 72 + dd]) * wgt;
                        float4 shp = *(const float4*)(s_sh + (et * 16 + el) * 8 + sb);
                        v0 = c[0] * xd * shp.x;
                        v1 = c[1] * xd * shp.y;
                        v2 = c[2] * xd * shp.z;
                        v3 = c[3] * xd * shp.w;
                    }
                    // weighted values: A-frag layout for K=16 MFMA (m=edge el, k=4q4+r)
                    bf16x4 aw;
                    aw.x = (short)f2b(v0); aw.y = (short)f2b(v1);
                    aw.z = (short)f2b(v2); aw.w = (short)f2b(v3);
#pragma unroll
                    for (int jt = 0; jt < 4; ++jt) {
                        bf16x4 bw = *(const bf16x4*)(wsw + WS_WO + (size_t)(ct * 4 + jt) * 256 + lane * 4);
                        accj[jt] = MFMA16(aw, bw, accj[jt]);
                    }
                }
            }
            // D[m=edge 4q4+r][n=j jt*16+el]: sum own 4 edges, then cross-q4 -> node sum
#pragma unroll
            for (int jt = 0; jt < 4; ++jt) {
                float s = accj[jt][0] + accj[jt][1] + accj[jt][2] + accj[jt][3];
                s += __shfl_xor(s, 16, 64);
                s += __shfl_xor(s, 32, 64);
                if (q4 == 0) s_yp[(w * 4 + et) * 64 + jt * 16 + el] = s;
            }
        }
    }
    __syncthreads();

    // ---------------- final: sum the 8 wave partials per node ----------------
    if (tid < 256) {
        int et = tid >> 6, j = tid & 63;
        float r = 0.f;
#pragma unroll
        for (int ww = 0; ww < 8; ++ww) r += s_yp[(ww * 4 + et) * 64 + j];
        out[(long)(n0 + et) * 64 + j] = r;
    }
}

extern "C" void kernel_launch(void* const* d_in, const int* in_sizes, int n_in,
                              void* d_out, int out_size, void* d_ws, size_t ws_size,
                              hipStream_t stream) {
    const float* node_feat = (const float*)d_in[0];
    const float* edge_sh   = (const float*)d_in[1];
    const float* edge_inv  = (const float*)d_in[2];
    const float* cutoff    = (const float*)d_in[3];
    const float* Wk1       = (const float*)d_in[4];
    const float* Wk2       = (const float*)d_in[5];
    const float* Wk3       = (const float*)d_in[6];
    const float* Wv1       = (const float*)d_in[7];
    const float* Wv2       = (const float*)d_in[8];
    const float* Wv3       = (const float*)d_in[9];
    const float* Wlogit    = (const float*)d_in[10];
    const float* Wout      = (const float*)d_in[11];
    const int*   edge_src  = (const int*)d_in[12];
    float* out = (float*)d_out;
    u16* wsw = (u16*)d_ws;

    prep<<<(WS_TOTAL + 255) / 256, 256, 0, stream>>>(
        Wk1, Wk2, Wk3, Wv1, Wv2, Wv3, Wout, wsw);
    fused<<<2048, 512, 0, stream>>>(
        node_feat, edge_sh, edge_inv, cutoff, Wlogit, edge_src, wsw, out);
}